// Round 1
// baseline (633.242 us; speedup 1.0000x reference)
//
#include <hip/hip_runtime.h>
#include <hip/hip_bf16.h>
#include <math.h>

// Problem constants
#define NT 2048      // tokens
#define EMBD 512
#define NH 8
#define HDIM 64
#define QKV_LD 1536  // qkv row stride

// ---------------- generic f32 GEMM: C[M][N] = A[M][K] @ B[K][N] + bias[N] ----
__global__ __launch_bounds__(256) void gemm_f32(const float* __restrict__ A,
    const float* __restrict__ B, const float* __restrict__ bias,
    float* __restrict__ C, int M, int N, int K)
{
    __shared__ float As[16][68];   // [kk][mm], stride 68 keeps rows 16B aligned
    __shared__ float Bs[16][68];   // [kk][nn]
    const int n0 = blockIdx.x << 6, m0 = blockIdx.y << 6;
    const int t = threadIdx.x, tx = t & 15, ty = t >> 4;
    float acc[4][4] = {};
    for (int kb = 0; kb < K; kb += 16) {
#pragma unroll
        for (int l = 0; l < 4; ++l) {
            int e = t + (l << 8);
            int mm = e >> 4, kk = e & 15;
            As[kk][mm] = A[(size_t)(m0 + mm) * K + kb + kk];
        }
#pragma unroll
        for (int l = 0; l < 4; ++l) {
            int e = t + (l << 8);
            int kk = e >> 6, nn = e & 63;
            Bs[kk][nn] = B[(size_t)(kb + kk) * N + n0 + nn];
        }
        __syncthreads();
#pragma unroll
        for (int kk = 0; kk < 16; ++kk) {
            float a[4], b[4];
#pragma unroll
            for (int i = 0; i < 4; ++i) a[i] = As[kk][(ty << 2) + i];
#pragma unroll
            for (int j = 0; j < 4; ++j) b[j] = Bs[kk][(tx << 2) + j];
#pragma unroll
            for (int i = 0; i < 4; ++i)
#pragma unroll
                for (int j = 0; j < 4; ++j)
                    acc[i][j] = fmaf(a[i], b[j], acc[i][j]);
        }
        __syncthreads();
    }
#pragma unroll
    for (int i = 0; i < 4; ++i) {
        int m = m0 + (ty << 2) + i;
#pragma unroll
        for (int j = 0; j < 4; ++j) {
            int n = n0 + (tx << 2) + j;
            C[(size_t)m * N + n] = acc[i][j] + bias[n];
        }
    }
}

// ---------------- scores: s[h][q][k] = (Q_h[q]·K_h[k]) * 0.125, bf16 out -----
__global__ __launch_bounds__(256) void scores_kernel(const float* __restrict__ qkv,
                                                     __hip_bfloat16* __restrict__ s)
{
    __shared__ float Qs[64][68];   // [t][q]  (transposed for contiguous q reads)
    __shared__ float Ks[64][68];   // [t][k]
    const int h = blockIdx.z;
    const int q0 = blockIdx.x << 6, k0 = blockIdx.y << 6;
    const int t = threadIdx.x, tx = t & 15, ty = t >> 4;
#pragma unroll
    for (int l = 0; l < 16; ++l) {
        int e = t + (l << 8);
        int rr = e >> 6, tt = e & 63;
        Qs[tt][rr] = qkv[(size_t)(q0 + rr) * QKV_LD + h * 192 + tt];
        Ks[tt][rr] = qkv[(size_t)(k0 + rr) * QKV_LD + h * 192 + 64 + tt];
    }
    __syncthreads();
    float acc[4][4] = {};
#pragma unroll 8
    for (int tt = 0; tt < 64; ++tt) {
        float a[4], b[4];
#pragma unroll
        for (int i = 0; i < 4; ++i) a[i] = Qs[tt][(ty << 2) + i];
#pragma unroll
        for (int j = 0; j < 4; ++j) b[j] = Ks[tt][(tx << 2) + j];
#pragma unroll
        for (int i = 0; i < 4; ++i)
#pragma unroll
            for (int j = 0; j < 4; ++j)
                acc[i][j] = fmaf(a[i], b[j], acc[i][j]);
    }
#pragma unroll
    for (int i = 0; i < 4; ++i) {
        int q = q0 + (ty << 2) + i;
#pragma unroll
        for (int j = 0; j < 4; ++j) {
            int k = k0 + (tx << 2) + j;
            s[((size_t)h * NT + q) * NT + k] = __float2bfloat16(acc[i][j] * 0.125f);
        }
    }
}

// ---------------- softmax stats: per row (h*2048+q) max and 1/sumexp ---------
__global__ __launch_bounds__(256) void softmax_stats(const __hip_bfloat16* __restrict__ s,
                                                     float* __restrict__ mOut,
                                                     float* __restrict__ izOut)
{
    const int row = blockIdx.x;
    const __hip_bfloat16* sr = s + (size_t)row * NT;
    const int t = threadIdx.x;
    float v[8];
    float m = -1e30f;
#pragma unroll
    for (int i = 0; i < 8; ++i) {
        v[i] = __bfloat162float(sr[t + (i << 8)]);
        m = fmaxf(m, v[i]);
    }
    __shared__ float red[256];
    red[t] = m; __syncthreads();
    for (int off = 128; off > 0; off >>= 1) {
        if (t < off) red[t] = fmaxf(red[t], red[t + off]);
        __syncthreads();
    }
    m = red[0];
    __syncthreads();
    float z = 0.f;
#pragma unroll
    for (int i = 0; i < 8; ++i) z += __expf(v[i] - m);
    red[t] = z; __syncthreads();
    for (int off = 128; off > 0; off >>= 1) {
        if (t < off) red[t] += red[t + off];
        __syncthreads();
    }
    if (t == 0) { mOut[row] = m; izOut[row] = 1.0f / red[0]; }
}

// ---------------- attn = softmax(s) + bias(angle), in place (bf16) ----------
__global__ __launch_bounds__(256) void bias_kernel(__hip_bfloat16* __restrict__ s,
    const float* __restrict__ vec, const float* __restrict__ Wb,
    const float* __restrict__ bb, const float* __restrict__ mbuf,
    const float* __restrict__ izbuf)
{
    __shared__ float wlds[64][8];
    __shared__ float blds[8];
    __shared__ float flds[32];
    const int t = threadIdx.x;
    for (int i = t; i < 512; i += 256) wlds[i >> 3][i & 7] = Wb[i];
    if (t < 8)  blds[t] = bb[t];
    if (t < 32) flds[t] = __fdiv_rn(__fdiv_rn((float)t, 31.0f), 0.1f);
    __syncthreads();

    const int p = blockIdx.x * 256 + t;
    const int q = p >> 11, k = p & 2047;
    // replicate numpy f32 dot: (p0+p1)+p2, no FMA contraction
    float a0 = vec[q * 3], a1 = vec[q * 3 + 1], a2 = vec[q * 3 + 2];
    float c0 = vec[k * 3], c1 = vec[k * 3 + 1], c2 = vec[k * 3 + 2];
    float dot = __fadd_rn(__fadd_rn(__fmul_rn(a0, c0), __fmul_rn(a1, c1)), __fmul_rn(a2, c2));
    float dotc = fminf(fmaxf(dot, 0.0f), 1.0f);
    float ang = __fdiv_rn(acosf(dotc), 0.001f);

    float bias[8];
#pragma unroll
    for (int h = 0; h < 8; ++h) bias[h] = 0.f;
#pragma unroll 4
    for (int i = 0; i < 32; ++i) {
        float ph = __fmul_rn(flds[i], ang);
        float rv = ph * 0.15915494309189535f;   // -> revolutions
        float rf = rv - floorf(rv);
        float si = __builtin_amdgcn_sinf(rf);   // sin(2*pi*rf)
        float ci = __builtin_amdgcn_cosf(rf);
#pragma unroll
        for (int h = 0; h < 8; ++h) {
            bias[h] = fmaf(si, wlds[i][h], bias[h]);
            bias[h] = fmaf(ci, wlds[i + 32][h], bias[h]);
        }
    }
    const size_t base = (size_t)q * NT + k;
#pragma unroll
    for (int h = 0; h < 8; ++h) {
        size_t idx = (size_t)h * (size_t)NT * NT + base;
        float sv = __bfloat162float(s[idx]);
        float m  = mbuf[h * NT + q];
        float iz = izbuf[h * NT + q];
        float attn = __expf(sv - m) * iz + bias[h] + blds[h];
        s[idx] = __float2bfloat16(attn);
    }
}

// ---------------- y[q][64h+t] = sum_k attn[h][q][k] * V_h[k][t] -------------
__global__ __launch_bounds__(256) void attnv_kernel(const __hip_bfloat16* __restrict__ s,
    const float* __restrict__ qkv, float* __restrict__ y)
{
    __shared__ float As2[32][68];  // [kk][qq]
    __shared__ float Vs[32][68];   // [kk][tt]
    const int h = blockIdx.y;
    const int q0 = blockIdx.x << 6;
    const int t = threadIdx.x, tx = t & 15, ty = t >> 4;
    float acc[4][4] = {};
    for (int k0 = 0; k0 < NT; k0 += 32) {
#pragma unroll
        for (int l = 0; l < 8; ++l) {
            int e = t + (l << 8);
            int qq = e >> 5, kk = e & 31;
            As2[kk][qq] = __bfloat162float(s[((size_t)h * NT + q0 + qq) * NT + k0 + kk]);
        }
#pragma unroll
        for (int l = 0; l < 8; ++l) {
            int e = t + (l << 8);
            int kk = e >> 6, tt = e & 63;
            Vs[kk][tt] = qkv[(size_t)(k0 + kk) * QKV_LD + h * 192 + 128 + tt];
        }
        __syncthreads();
#pragma unroll 8
        for (int kk = 0; kk < 32; ++kk) {
            float a[4], b[4];
#pragma unroll
            for (int i = 0; i < 4; ++i) a[i] = As2[kk][(ty << 2) + i];
#pragma unroll
            for (int j = 0; j < 4; ++j) b[j] = Vs[kk][(tx << 2) + j];
#pragma unroll
            for (int i = 0; i < 4; ++i)
#pragma unroll
                for (int j = 0; j < 4; ++j)
                    acc[i][j] = fmaf(a[i], b[j], acc[i][j]);
        }
        __syncthreads();
    }
#pragma unroll
    for (int i = 0; i < 4; ++i) {
        int q = q0 + (ty << 2) + i;
#pragma unroll
        for (int j = 0; j < 4; ++j)
            y[(size_t)q * EMBD + (h << 6) + (tx << 2) + j] = acc[i][j];
    }
}

extern "C" void kernel_launch(void* const* d_in, const int* in_sizes, int n_in,
                              void* d_out, int out_size, void* d_ws, size_t ws_size,
                              hipStream_t stream)
{
    const float* x    = (const float*)d_in[0];
    const float* vec  = (const float*)d_in[1];
    const float* Wqkv = (const float*)d_in[2];
    const float* bqkv = (const float*)d_in[3];
    const float* Wb   = (const float*)d_in[4];
    const float* bb   = (const float*)d_in[5];
    const float* Wout = (const float*)d_in[6];
    const float* bout = (const float*)d_in[7];
    float* out = (float*)d_out;

    char* ws = (char*)d_ws;
    float*          qkv  = (float*)(ws);                         // 12,582,912 B
    __hip_bfloat16* sbuf = (__hip_bfloat16*)(ws + 12582912);     // 67,108,864 B
    float*          mbuf = (float*)(ws + 79691776);              //     65,536 B
    float*          izb  = (float*)(ws + 79757312);              //     65,536 B
    float*          ybuf = (float*)(ws + 79822848);              //  4,194,304 B
    // total ws use: 84,017,152 B

    // 1) qkv = x @ W_qkv + b_qkv
    gemm_f32<<<dim3(24, 32), 256, 0, stream>>>(x, Wqkv, bqkv, qkv, NT, QKV_LD, EMBD);
    // 2) s[h][q][k] = Q·K/8  (bf16)
    scores_kernel<<<dim3(32, 32, 8), 256, 0, stream>>>(qkv, sbuf);
    // 3) per-row softmax stats
    softmax_stats<<<NT * NH, 256, 0, stream>>>(sbuf, mbuf, izb);
    // 4) attn = softmax + positional bias   (in place)
    bias_kernel<<<(NT * NT) / 256, 256, 0, stream>>>(sbuf, vec, Wb, bb, mbuf, izb);
    // 5) y = attn @ v
    attnv_kernel<<<dim3(32, 8), 256, 0, stream>>>(sbuf, qkv, ybuf);
    // 6) out = y @ W_out + b_out
    gemm_f32<<<dim3(8, 32), 256, 0, stream>>>(ybuf, Wout, bout, out, NT, EMBD, EMBD);
}

// Round 2
// 602.062 us; speedup vs baseline: 1.0518x; 1.0518x over previous
//
#include <hip/hip_runtime.h>
#include <hip/hip_bf16.h>
#include <math.h>

#define NT 2048
#define EMBD 512
#define NH 8
#define QKV_LD 1536

static __device__ __forceinline__ float bf2f(unsigned int u) {
    union { unsigned int i; float f; } c; c.i = u << 16; return c.f;
}
static __device__ __forceinline__ void unpack8(uint4 r, float* f) {
    f[0] = bf2f(r.x & 0xffffu); f[1] = bf2f(r.x >> 16);
    f[2] = bf2f(r.y & 0xffffu); f[3] = bf2f(r.y >> 16);
    f[4] = bf2f(r.z & 0xffffu); f[5] = bf2f(r.z >> 16);
    f[6] = bf2f(r.w & 0xffffu); f[7] = bf2f(r.w >> 16);
}

// ---------------- f32 GEMM with bias: C = A[M][K] @ B[K][N] + bias ----------
__global__ __launch_bounds__(256) void gemm_f32(const float* __restrict__ A,
    const float* __restrict__ B, const float* __restrict__ bias,
    float* __restrict__ C, int M, int N, int K)
{
    __shared__ float As[16][68];
    __shared__ float Bs[16][68];
    const int n0 = blockIdx.x << 6, m0 = blockIdx.y << 6;
    const int t = threadIdx.x, tx = t & 15, ty = t >> 4;
    float acc[4][4] = {};
    for (int kb = 0; kb < K; kb += 16) {
#pragma unroll
        for (int l = 0; l < 4; ++l) {
            int e = t + (l << 8);
            int mm = e >> 4, kk = e & 15;
            As[kk][mm] = A[(size_t)(m0 + mm) * K + kb + kk];
        }
#pragma unroll
        for (int l = 0; l < 4; ++l) {
            int e = t + (l << 8);
            int kk = e >> 6, nn = e & 63;
            Bs[kk][nn] = B[(size_t)(kb + kk) * N + n0 + nn];
        }
        __syncthreads();
#pragma unroll
        for (int kk = 0; kk < 16; ++kk) {
            float a[4], b[4];
#pragma unroll
            for (int i = 0; i < 4; ++i) a[i] = As[kk][(ty << 2) + i];
#pragma unroll
            for (int j = 0; j < 4; ++j) b[j] = Bs[kk][(tx << 2) + j];
#pragma unroll
            for (int i = 0; i < 4; ++i)
#pragma unroll
                for (int j = 0; j < 4; ++j)
                    acc[i][j] = fmaf(a[i], b[j], acc[i][j]);
        }
        __syncthreads();
    }
#pragma unroll
    for (int i = 0; i < 4; ++i) {
        int m = m0 + (ty << 2) + i;
#pragma unroll
        for (int j = 0; j < 4; ++j) {
            int n = n0 + (tx << 2) + j;
            C[(size_t)m * N + n] = acc[i][j] + bias[n];
        }
    }
}

// ---------------- f32 GEMM partial (split-K, no bias) -----------------------
__global__ __launch_bounds__(256) void gemm_f32_part(const float* __restrict__ A,
    const float* __restrict__ B, float* __restrict__ Cpart,
    int M, int N, int KS)
{
    __shared__ float As[16][68];
    __shared__ float Bs[16][68];
    const int n0 = blockIdx.x << 6, m0 = blockIdx.y << 6;
    const int kstart = blockIdx.z * KS;
    const int K = 512;  // A row stride for out-proj use
    const int t = threadIdx.x, tx = t & 15, ty = t >> 4;
    float acc[4][4] = {};
    for (int kb = kstart; kb < kstart + KS; kb += 16) {
#pragma unroll
        for (int l = 0; l < 4; ++l) {
            int e = t + (l << 8);
            int mm = e >> 4, kk = e & 15;
            As[kk][mm] = A[(size_t)(m0 + mm) * K + kb + kk];
        }
#pragma unroll
        for (int l = 0; l < 4; ++l) {
            int e = t + (l << 8);
            int kk = e >> 6, nn = e & 63;
            Bs[kk][nn] = B[(size_t)(kb + kk) * N + n0 + nn];
        }
        __syncthreads();
#pragma unroll
        for (int kk = 0; kk < 16; ++kk) {
            float a[4], b[4];
#pragma unroll
            for (int i = 0; i < 4; ++i) a[i] = As[kk][(ty << 2) + i];
#pragma unroll
            for (int j = 0; j < 4; ++j) b[j] = Bs[kk][(tx << 2) + j];
#pragma unroll
            for (int i = 0; i < 4; ++i)
#pragma unroll
                for (int j = 0; j < 4; ++j)
                    acc[i][j] = fmaf(a[i], b[j], acc[i][j]);
        }
        __syncthreads();
    }
    float* Cz = Cpart + (size_t)blockIdx.z * M * N;
#pragma unroll
    for (int i = 0; i < 4; ++i) {
        int m = m0 + (ty << 2) + i;
#pragma unroll
        for (int j = 0; j < 4; ++j) {
            int n = n0 + (tx << 2) + j;
            Cz[(size_t)m * N + n] = acc[i][j];
        }
    }
}

// ---------------- scores: s[h][q][k] = (Q_h[q]·K_h[k]) * 0.125, bf16 out -----
__global__ __launch_bounds__(256) void scores_kernel(const float* __restrict__ qkv,
                                                     __hip_bfloat16* __restrict__ s)
{
    __shared__ float Qs[64][68];
    __shared__ float Ks[64][68];
    const int h = blockIdx.z;
    const int q0 = blockIdx.x << 6, k0 = blockIdx.y << 6;
    const int t = threadIdx.x, tx = t & 15, ty = t >> 4;
#pragma unroll
    for (int l = 0; l < 16; ++l) {
        int e = t + (l << 8);
        int rr = e >> 6, tt = e & 63;
        Qs[tt][rr] = qkv[(size_t)(q0 + rr) * QKV_LD + h * 192 + tt];
        Ks[tt][rr] = qkv[(size_t)(k0 + rr) * QKV_LD + h * 192 + 64 + tt];
    }
    __syncthreads();
    float acc[4][4] = {};
#pragma unroll 8
    for (int tt = 0; tt < 64; ++tt) {
        float a[4], b[4];
#pragma unroll
        for (int i = 0; i < 4; ++i) a[i] = Qs[tt][(ty << 2) + i];
#pragma unroll
        for (int j = 0; j < 4; ++j) b[j] = Ks[tt][(tx << 2) + j];
#pragma unroll
        for (int i = 0; i < 4; ++i)
#pragma unroll
            for (int j = 0; j < 4; ++j)
                acc[i][j] = fmaf(a[i], b[j], acc[i][j]);
    }
#pragma unroll
    for (int i = 0; i < 4; ++i) {
        int q = q0 + (ty << 2) + i;
#pragma unroll
        for (int j = 0; j < 4; ++j) {
            int k = k0 + (tx << 2) + j;
            s[((size_t)h * NT + q) * NT + k] = __float2bfloat16(acc[i][j] * 0.125f);
        }
    }
}

// ---------------- softmax stats ---------------------------------------------
__global__ __launch_bounds__(256) void softmax_stats(const __hip_bfloat16* __restrict__ s,
                                                     float* __restrict__ mOut,
                                                     float* __restrict__ izOut)
{
    const int row = blockIdx.x;
    const int t = threadIdx.x;
    const uint4 raw = *(const uint4*)((const unsigned short*)s + (size_t)row * NT + (t << 3));
    float v[8]; unpack8(raw, v);
    float m = v[0];
#pragma unroll
    for (int i = 1; i < 8; ++i) m = fmaxf(m, v[i]);
    __shared__ float red[256];
    red[t] = m; __syncthreads();
    for (int off = 128; off > 0; off >>= 1) {
        if (t < off) red[t] = fmaxf(red[t], red[t + off]);
        __syncthreads();
    }
    m = red[0];
    __syncthreads();
    float z = 0.f;
#pragma unroll
    for (int i = 0; i < 8; ++i) z += __expf(v[i] - m);
    red[t] = z; __syncthreads();
    for (int off = 128; off > 0; off >>= 1) {
        if (t < off) red[t] += red[t + off];
        __syncthreads();
    }
    if (t == 0) { mOut[row] = m; izOut[row] = 1.0f / red[0]; }
}

// ---------------- attn = softmax(s) + bias(angle), triangle, f64 angle ------
__global__ __launch_bounds__(256) void bias_kernel(__hip_bfloat16* __restrict__ s,
    const float* __restrict__ vec, const float* __restrict__ Wb,
    const float* __restrict__ bb, const float* __restrict__ mbuf,
    const float* __restrict__ izbuf)
{
    const int tq = blockIdx.x, tk = blockIdx.y;
    if (tk < tq) return;
    const int t = threadIdx.x;
    const int q = (tq << 4) + (t >> 4);
    const int k = (tk << 4) + (t & 15);
    if (q > k) return;

    // f64 dot (exact for f32 inputs), clip, acos, /0.001 — matches an f64 ref
    double a0 = (double)vec[q * 3],     a1 = (double)vec[q * 3 + 1], a2 = (double)vec[q * 3 + 2];
    double c0 = (double)vec[k * 3],     c1d = (double)vec[k * 3 + 1], c2 = (double)vec[k * 3 + 2];
    double dot = a0 * c0 + a1 * c1d + a2 * c2;
    dot = fmin(fmax(dot, 0.0), 1.0);
    double ang = acos(dot) / 0.001;

    // harmonic recurrence: phase_i = i * theta1, theta1 = ang * f1
    const double F1_OVER_2PI = ((1.0 / 31.0) / 0.1) / 6.283185307179586476925286766559;
    double rv = ang * F1_OVER_2PI;
    float rf = (float)(rv - floor(rv));
    float s1 = __builtin_amdgcn_sinf(rf);   // sin(2*pi*rf)
    float c1 = __builtin_amdgcn_cosf(rf);

    float bias[8];
#pragma unroll
    for (int h = 0; h < 8; ++h) bias[h] = bb[h];
    float si = 0.f, ci = 1.f;
#pragma unroll
    for (int i = 0; i < 32; ++i) {
#pragma unroll
        for (int h = 0; h < 8; ++h) {
            bias[h] = fmaf(si, Wb[i * 8 + h], bias[h]);
            bias[h] = fmaf(ci, Wb[(i + 32) * 8 + h], bias[h]);
        }
        float ns = fmaf(si, c1, ci * s1);
        float nc = fmaf(ci, c1, -si * s1);
        si = ns; ci = nc;
    }

#pragma unroll
    for (int h = 0; h < 8; ++h) {
        size_t i1 = ((size_t)h * NT + q) * NT + k;
        float sv = __bfloat162float(s[i1]);
        float attn = __expf(sv - mbuf[h * NT + q]) * izbuf[h * NT + q] + bias[h];
        s[i1] = __float2bfloat16(attn);
        if (k != q) {
            size_t i2 = ((size_t)h * NT + k) * NT + q;
            float sv2 = __bfloat162float(s[i2]);
            float attn2 = __expf(sv2 - mbuf[h * NT + k]) * izbuf[h * NT + k] + bias[h];
            s[i2] = __float2bfloat16(attn2);
        }
    }
}

// ---------------- y_part = attn @ V over a K split --------------------------
__global__ __launch_bounds__(256) void attnv_split(const __hip_bfloat16* __restrict__ s,
    const float* __restrict__ qkv, float* __restrict__ ypart)
{
    __shared__ float As2[64][33];   // [qq][kk], stride 33: conflict-free writes
    __shared__ float Vs[32][68];    // [kk][tt], b128-readable
    const int h = blockIdx.y;
    const int q0 = blockIdx.x << 6;
    const int kbase = blockIdx.z << 9;   // 512-wide K split
    const int t = threadIdx.x;
    const int tx = t & 7, ty = t >> 3;   // per-thread 2q x 8t
    const int sqq = t >> 2;              // staging: row 0..63
    const int skk = (t & 3) << 3;        // staging: col {0,8,16,24}
    float acc[2][8] = {};
    for (int k0 = kbase; k0 < kbase + 512; k0 += 32) {
        uint4 araw = *(const uint4*)((const unsigned short*)s +
                     ((size_t)(h * NT + q0 + sqq)) * NT + k0 + skk);
        float af[8]; unpack8(araw, af);
#pragma unroll
        for (int j = 0; j < 8; ++j) As2[sqq][skk + j] = af[j];
#pragma unroll
        for (int l = 0; l < 2; ++l) {
            int e = t + (l << 8);
            int kk = e >> 4, t4 = (e & 15) << 2;
            *(float4*)&Vs[kk][t4] =
                *(const float4*)(qkv + (size_t)(k0 + kk) * QKV_LD + h * 192 + 128 + t4);
        }
        __syncthreads();
#pragma unroll 4
        for (int kk = 0; kk < 32; ++kk) {
            float a0v = As2[(ty << 1)][kk];
            float a1v = As2[(ty << 1) + 1][kk];
            float b[8];
#pragma unroll
            for (int j = 0; j < 8; ++j) b[j] = Vs[kk][(tx << 3) + j];
#pragma unroll
            for (int j = 0; j < 8; ++j) {
                acc[0][j] = fmaf(a0v, b[j], acc[0][j]);
                acc[1][j] = fmaf(a1v, b[j], acc[1][j]);
            }
        }
        __syncthreads();
    }
    float* yp = ypart + (size_t)blockIdx.z * (NT * EMBD);
#pragma unroll
    for (int i = 0; i < 2; ++i) {
        int q = q0 + (ty << 1) + i;
        float4* dst = (float4*)(yp + (size_t)q * EMBD + (h << 6) + (tx << 3));
        dst[0] = make_float4(acc[i][0], acc[i][1], acc[i][2], acc[i][3]);
        dst[1] = make_float4(acc[i][4], acc[i][5], acc[i][6], acc[i][7]);
    }
}

// ---------------- reduce partials (+optional bias) --------------------------
__global__ __launch_bounds__(256) void reduce_add(float* __restrict__ out,
    const float* __restrict__ parts, const float* __restrict__ bias,
    int nsplit, int MN, int N)
{
    int i = (blockIdx.x * 256 + threadIdx.x) << 2;
    if (i >= MN) return;
    float4 acc = *(const float4*)(parts + i);
    for (int sp = 1; sp < nsplit; ++sp) {
        float4 p = *(const float4*)(parts + (size_t)sp * MN + i);
        acc.x += p.x; acc.y += p.y; acc.z += p.z; acc.w += p.w;
    }
    if (bias) {
        float4 b = *(const float4*)(bias + (i & (N - 1)));
        acc.x += b.x; acc.y += b.y; acc.z += b.z; acc.w += b.w;
    }
    *(float4*)(out + i) = acc;
}

extern "C" void kernel_launch(void* const* d_in, const int* in_sizes, int n_in,
                              void* d_out, int out_size, void* d_ws, size_t ws_size,
                              hipStream_t stream)
{
    const float* x    = (const float*)d_in[0];
    const float* vec  = (const float*)d_in[1];
    const float* Wqkv = (const float*)d_in[2];
    const float* bqkv = (const float*)d_in[3];
    const float* Wb   = (const float*)d_in[4];
    const float* bb   = (const float*)d_in[5];
    const float* Wout = (const float*)d_in[6];
    const float* bout = (const float*)d_in[7];
    float* out = (float*)d_out;

    char* ws = (char*)d_ws;
    float*          qkv   = (float*)(ws);                      // 12,582,912
    __hip_bfloat16* sbuf  = (__hip_bfloat16*)(ws + 12582912);  // 67,108,864
    float*          mbuf  = (float*)(ws + 79691776);           //     65,536
    float*          izb   = (float*)(ws + 79757312);           //     65,536
    float*          ybuf  = (float*)(ws + 79822848);           //  4,194,304
    float*          parts = (float*)(ws + 84017152);           // 16,777,216
    // total: 100,794,368 B

    // 1) qkv = x @ W_qkv + b_qkv
    gemm_f32<<<dim3(24, 32), 256, 0, stream>>>(x, Wqkv, bqkv, qkv, NT, QKV_LD, EMBD);
    // 2) s = Q·K/8 (bf16)
    scores_kernel<<<dim3(32, 32, 8), 256, 0, stream>>>(qkv, sbuf);
    // 3) softmax stats
    softmax_stats<<<NT * NH, 256, 0, stream>>>(sbuf, mbuf, izb);
    // 4) attn = softmax + bias (triangle, f64 angle)
    bias_kernel<<<dim3(128, 128), 256, 0, stream>>>(sbuf, vec, Wb, bb, mbuf, izb);
    // 5) y = attn @ v (split-K=4 partials)
    attnv_split<<<dim3(32, 8, 4), 256, 0, stream>>>(sbuf, qkv, parts);
    reduce_add<<<1024, 256, 0, stream>>>(ybuf, parts, nullptr, 4, NT * EMBD, EMBD);
    // 6) out = y @ W_out + b_out (split-K=4 partials)
    gemm_f32_part<<<dim3(8, 32, 4), 256, 0, stream>>>(ybuf, Wout, parts, NT, EMBD, 128);
    reduce_add<<<1024, 256, 0, stream>>>(out, parts, bout, 4, NT * EMBD, EMBD);
}

// Round 3
// 354.263 us; speedup vs baseline: 1.7875x; 1.6995x over previous
//
#include <hip/hip_runtime.h>
#include <hip/hip_bf16.h>
#include <math.h>

#define NT 2048
#define EMBD 512
#define NH 8
#define QKV_LD 1536

static __device__ __forceinline__ float bf2f(unsigned int u) {
    union { unsigned int i; float f; } c; c.i = u << 16; return c.f;
}
static __device__ __forceinline__ void unpack8(uint4 r, float* f) {
    f[0] = bf2f(r.x & 0xffffu); f[1] = bf2f(r.x >> 16);
    f[2] = bf2f(r.y & 0xffffu); f[3] = bf2f(r.y >> 16);
    f[4] = bf2f(r.z & 0xffffu); f[5] = bf2f(r.z >> 16);
    f[6] = bf2f(r.w & 0xffffu); f[7] = bf2f(r.w >> 16);
}
static __device__ __forceinline__ void unpack4(uint2 r, float* f) {
    f[0] = bf2f(r.x & 0xffffu); f[1] = bf2f(r.x >> 16);
    f[2] = bf2f(r.y & 0xffffu); f[3] = bf2f(r.y >> 16);
}
static __device__ __forceinline__ unsigned int f2bf(float x) {   // RNE, matches __float2bfloat16
    union { float f; unsigned int u; } c; c.f = x;
    return (c.u + 0x7fffu + ((c.u >> 16) & 1u)) >> 16;
}

// ---------------- f32 GEMM with bias: C = A[M][K] @ B[K][N] + bias ----------
__global__ __launch_bounds__(256) void gemm_f32(const float* __restrict__ A,
    const float* __restrict__ B, const float* __restrict__ bias,
    float* __restrict__ C, int M, int N, int K)
{
    __shared__ float As[16][68];
    __shared__ float Bs[16][68];
    const int n0 = blockIdx.x << 6, m0 = blockIdx.y << 6;
    const int t = threadIdx.x, tx = t & 15, ty = t >> 4;
    float acc[4][4] = {};
    for (int kb = 0; kb < K; kb += 16) {
#pragma unroll
        for (int l = 0; l < 4; ++l) {
            int e = t + (l << 8);
            int mm = e >> 4, kk = e & 15;
            As[kk][mm] = A[(size_t)(m0 + mm) * K + kb + kk];
        }
#pragma unroll
        for (int l = 0; l < 4; ++l) {
            int e = t + (l << 8);
            int kk = e >> 6, nn = e & 63;
            Bs[kk][nn] = B[(size_t)(kb + kk) * N + n0 + nn];
        }
        __syncthreads();
#pragma unroll
        for (int kk = 0; kk < 16; ++kk) {
            float a[4], b[4];
#pragma unroll
            for (int i = 0; i < 4; ++i) a[i] = As[kk][(ty << 2) + i];
#pragma unroll
            for (int j = 0; j < 4; ++j) b[j] = Bs[kk][(tx << 2) + j];
#pragma unroll
            for (int i = 0; i < 4; ++i)
#pragma unroll
                for (int j = 0; j < 4; ++j)
                    acc[i][j] = fmaf(a[i], b[j], acc[i][j]);
        }
        __syncthreads();
    }
#pragma unroll
    for (int i = 0; i < 4; ++i) {
        int m = m0 + (ty << 2) + i;
#pragma unroll
        for (int j = 0; j < 4; ++j) {
            int n = n0 + (tx << 2) + j;
            C[(size_t)m * N + n] = acc[i][j] + bias[n];
        }
    }
}

// ---------------- f32 GEMM partial (split-K, no bias), K=512 stride ---------
__global__ __launch_bounds__(256) void gemm_f32_part(const float* __restrict__ A,
    const float* __restrict__ B, float* __restrict__ Cpart,
    int M, int N, int KS)
{
    __shared__ float As[16][68];
    __shared__ float Bs[16][68];
    const int n0 = blockIdx.x << 6, m0 = blockIdx.y << 6;
    const int kstart = blockIdx.z * KS;
    const int K = 512;
    const int t = threadIdx.x, tx = t & 15, ty = t >> 4;
    float acc[4][4] = {};
    for (int kb = kstart; kb < kstart + KS; kb += 16) {
#pragma unroll
        for (int l = 0; l < 4; ++l) {
            int e = t + (l << 8);
            int mm = e >> 4, kk = e & 15;
            As[kk][mm] = A[(size_t)(m0 + mm) * K + kb + kk];
        }
#pragma unroll
        for (int l = 0; l < 4; ++l) {
            int e = t + (l << 8);
            int kk = e >> 6, nn = e & 63;
            Bs[kk][nn] = B[(size_t)(kb + kk) * N + n0 + nn];
        }
        __syncthreads();
#pragma unroll
        for (int kk = 0; kk < 16; ++kk) {
            float a[4], b[4];
#pragma unroll
            for (int i = 0; i < 4; ++i) a[i] = As[kk][(ty << 2) + i];
#pragma unroll
            for (int j = 0; j < 4; ++j) b[j] = Bs[kk][(tx << 2) + j];
#pragma unroll
            for (int i = 0; i < 4; ++i)
#pragma unroll
                for (int j = 0; j < 4; ++j)
                    acc[i][j] = fmaf(a[i], b[j], acc[i][j]);
        }
        __syncthreads();
    }
    float* Cz = Cpart + (size_t)blockIdx.z * M * N;
#pragma unroll
    for (int i = 0; i < 4; ++i) {
        int m = m0 + (ty << 2) + i;
#pragma unroll
        for (int j = 0; j < 4; ++j) {
            int n = n0 + (tx << 2) + j;
            Cz[(size_t)m * N + n] = acc[i][j];
        }
    }
}

// ---------------- scores: s[h][q][k] = (Q_h[q]·K_h[k]) * 0.125, bf16 out -----
__global__ __launch_bounds__(256) void scores_kernel(const float* __restrict__ qkv,
                                                     __hip_bfloat16* __restrict__ s)
{
    __shared__ float Qs[64][68];
    __shared__ float Ks[64][68];
    const int h = blockIdx.z;
    const int q0 = blockIdx.x << 6, k0 = blockIdx.y << 6;
    const int t = threadIdx.x, tx = t & 15, ty = t >> 4;
#pragma unroll
    for (int l = 0; l < 16; ++l) {
        int e = t + (l << 8);
        int rr = e >> 6, tt = e & 63;
        Qs[tt][rr] = qkv[(size_t)(q0 + rr) * QKV_LD + h * 192 + tt];
        Ks[tt][rr] = qkv[(size_t)(k0 + rr) * QKV_LD + h * 192 + 64 + tt];
    }
    __syncthreads();
    float acc[4][4] = {};
#pragma unroll 8
    for (int tt = 0; tt < 64; ++tt) {
        float a[4], b[4];
#pragma unroll
        for (int i = 0; i < 4; ++i) a[i] = Qs[tt][(ty << 2) + i];
#pragma unroll
        for (int j = 0; j < 4; ++j) b[j] = Ks[tt][(tx << 2) + j];
#pragma unroll
        for (int i = 0; i < 4; ++i)
#pragma unroll
            for (int j = 0; j < 4; ++j)
                acc[i][j] = fmaf(a[i], b[j], acc[i][j]);
    }
#pragma unroll
    for (int i = 0; i < 4; ++i) {
        int q = q0 + (ty << 2) + i;
#pragma unroll
        for (int j = 0; j < 4; ++j) {
            int k = k0 + (tx << 2) + j;
            s[((size_t)h * NT + q) * NT + k] = __float2bfloat16(acc[i][j] * 0.125f);
        }
    }
}

// ---------------- softmax stats ---------------------------------------------
__global__ __launch_bounds__(256) void softmax_stats(const __hip_bfloat16* __restrict__ s,
                                                     float* __restrict__ mOut,
                                                     float* __restrict__ izOut)
{
    const int row = blockIdx.x;
    const int t = threadIdx.x;
    const uint4 raw = *(const uint4*)((const unsigned short*)s + (size_t)row * NT + (t << 3));
    float v[8]; unpack8(raw, v);
    float m = v[0];
#pragma unroll
    for (int i = 1; i < 8; ++i) m = fmaxf(m, v[i]);
    __shared__ float red[256];
    red[t] = m; __syncthreads();
    for (int off = 128; off > 0; off >>= 1) {
        if (t < off) red[t] = fmaxf(red[t], red[t + off]);
        __syncthreads();
    }
    m = red[0];
    __syncthreads();
    float z = 0.f;
#pragma unroll
    for (int i = 0; i < 8; ++i) z += __expf(v[i] - m);
    red[t] = z; __syncthreads();
    for (int off = 128; off > 0; off >>= 1) {
        if (t < off) red[t] += red[t + off];
        __syncthreads();
    }
    if (t == 0) { mOut[row] = m; izOut[row] = 1.0f / red[0]; }
}

// ---- attn = softmax(s)+bias: triangular 32x32 tiles, R1 f32 numerics -------
__global__ __launch_bounds__(256) void bias_kernel(__hip_bfloat16* __restrict__ s,
    const float* __restrict__ vec, const float* __restrict__ Wb,
    const float* __restrict__ bb, const float* __restrict__ mbuf,
    const float* __restrict__ izbuf)
{
    __shared__ float wlds[64][8];
    __shared__ float flds[32];
    __shared__ float vql[96], vkl[96];
    __shared__ float bbl[8];
    __shared__ float bias_lds[8][32][33];   // [h][qq][kk], stride 33

    const int t = threadIdx.x;
    // triangular tile decode: blockIdx.x -> (tq, tk), tk >= tq, 32x32 tiles
    int b = blockIdx.x, tq = 0, rem = 64;
    while (b >= rem) { b -= rem; ++tq; --rem; }
    const int tk = tq + b;
    const int q0 = tq << 5, k0 = tk << 5;

    for (int i = t; i < 512; i += 256) wlds[i >> 3][i & 7] = Wb[i];
    if (t < 32) flds[t] = __fdiv_rn(__fdiv_rn((float)t, 31.0f), 0.1f);
    if (t < 96) vql[t] = vec[q0 * 3 + t];
    else if (t < 192) vkl[t - 96] = vec[k0 * 3 + (t - 96)];
    else if (t < 200) bbl[t - 192] = bb[t - 192];
    __syncthreads();

    // ---- phase 1: compute bias for 1q x 4k pairs per thread ----
    {
        const int qq = t & 31;
        const int kb = (t >> 5) << 2;
        const float a0 = vql[qq * 3], a1 = vql[qq * 3 + 1], a2 = vql[qq * 3 + 2];
        float ang[4];
#pragma unroll
        for (int j = 0; j < 4; ++j) {
            const int kk = kb + j;
            float c0 = vkl[kk * 3], c1 = vkl[kk * 3 + 1], c2 = vkl[kk * 3 + 2];
            // replicate numpy f32 dot: (p0+p1)+p2, no FMA
            float dot = __fadd_rn(__fadd_rn(__fmul_rn(a0, c0), __fmul_rn(a1, c1)),
                                  __fmul_rn(a2, c2));
            float dotc = fminf(fmaxf(dot, 0.0f), 1.0f);
            ang[j] = __fdiv_rn(acosf(dotc), 0.001f);
        }
        float bacc[4][8] = {};
#pragma unroll 4
        for (int i = 0; i < 32; ++i) {
            float ws[8], wc[8];
#pragma unroll
            for (int h = 0; h < 8; ++h) { ws[h] = wlds[i][h]; wc[h] = wlds[i + 32][h]; }
            const float fi = flds[i];
#pragma unroll
            for (int j = 0; j < 4; ++j) {
                float ph = __fmul_rn(fi, ang[j]);
                float rv = ph * 0.15915494309189535f;
                float rf = rv - floorf(rv);
                float si = __builtin_amdgcn_sinf(rf);
                float ci = __builtin_amdgcn_cosf(rf);
#pragma unroll
                for (int h = 0; h < 8; ++h) {
                    bacc[j][h] = fmaf(si, ws[h], bacc[j][h]);
                    bacc[j][h] = fmaf(ci, wc[h], bacc[j][h]);
                }
            }
        }
#pragma unroll
        for (int j = 0; j < 4; ++j)
#pragma unroll
            for (int h = 0; h < 8; ++h)
                bias_lds[h][qq][kb + j] = bacc[j][h];
    }
    __syncthreads();

    // ---- phase 2: apply softmax + bias, coalesced RMW (both orientations) --
    const int r = t >> 3;
    const int cg = (t & 7) << 2;
    unsigned short* sp = (unsigned short*)s;
    {
        const int q = q0 + r;
#pragma unroll
        for (int h = 0; h < 8; ++h) {
            const float m = mbuf[h * NT + q], iz = izbuf[h * NT + q], bv = bbl[h];
            const size_t base = ((size_t)h * NT + q) * NT + k0 + cg;
            uint2 raw = *(const uint2*)(sp + base);
            float v[4]; unpack4(raw, v);
            unsigned int o[4];
#pragma unroll
            for (int j = 0; j < 4; ++j) {
                float val = __expf(v[j] - m) * iz + bias_lds[h][r][cg + j] + bv;
                o[j] = f2bf(val);
            }
            uint2 w; w.x = o[0] | (o[1] << 16); w.y = o[2] | (o[3] << 16);
            *(uint2*)(sp + base) = w;
        }
    }
    if (tk != tq) {
        const int q = k0 + r;
#pragma unroll
        for (int h = 0; h < 8; ++h) {
            const float m = mbuf[h * NT + q], iz = izbuf[h * NT + q], bv = bbl[h];
            const size_t base = ((size_t)h * NT + q) * NT + q0 + cg;
            uint2 raw = *(const uint2*)(sp + base);
            float v[4]; unpack4(raw, v);
            unsigned int o[4];
#pragma unroll
            for (int j = 0; j < 4; ++j) {
                float val = __expf(v[j] - m) * iz + bias_lds[h][cg + j][r] + bv;
                o[j] = f2bf(val);
            }
            uint2 w; w.x = o[0] | (o[1] << 16); w.y = o[2] | (o[3] << 16);
            *(uint2*)(sp + base) = w;
        }
    }
}

// ---------------- y_part = attn @ V over a K split --------------------------
__global__ __launch_bounds__(256) void attnv_split(const __hip_bfloat16* __restrict__ s,
    const float* __restrict__ qkv, float* __restrict__ ypart)
{
    __shared__ float As2[64][33];
    __shared__ float Vs[32][68];
    const int h = blockIdx.y;
    const int q0 = blockIdx.x << 6;
    const int kbase = blockIdx.z << 9;
    const int t = threadIdx.x;
    const int tx = t & 7, ty = t >> 3;
    const int sqq = t >> 2;
    const int skk = (t & 3) << 3;
    float acc[2][8] = {};
    for (int k0 = kbase; k0 < kbase + 512; k0 += 32) {
        uint4 araw = *(const uint4*)((const unsigned short*)s +
                     ((size_t)(h * NT + q0 + sqq)) * NT + k0 + skk);
        float af[8]; unpack8(araw, af);
#pragma unroll
        for (int j = 0; j < 8; ++j) As2[sqq][skk + j] = af[j];
#pragma unroll
        for (int l = 0; l < 2; ++l) {
            int e = t + (l << 8);
            int kk = e >> 4, t4 = (e & 15) << 2;
            *(float4*)&Vs[kk][t4] =
                *(const float4*)(qkv + (size_t)(k0 + kk) * QKV_LD + h * 192 + 128 + t4);
        }
        __syncthreads();
#pragma unroll 4
        for (int kk = 0; kk < 32; ++kk) {
            float a0v = As2[(ty << 1)][kk];
            float a1v = As2[(ty << 1) + 1][kk];
            float b[8];
#pragma unroll
            for (int j = 0; j < 8; ++j) b[j] = Vs[kk][(tx << 3) + j];
#pragma unroll
            for (int j = 0; j < 8; ++j) {
                acc[0][j] = fmaf(a0v, b[j], acc[0][j]);
                acc[1][j] = fmaf(a1v, b[j], acc[1][j]);
            }
        }
        __syncthreads();
    }
    float* yp = ypart + (size_t)blockIdx.z * (NT * EMBD);
#pragma unroll
    for (int i = 0; i < 2; ++i) {
        int q = q0 + (ty << 1) + i;
        float4* dst = (float4*)(yp + (size_t)q * EMBD + (h << 6) + (tx << 3));
        dst[0] = make_float4(acc[i][0], acc[i][1], acc[i][2], acc[i][3]);
        dst[1] = make_float4(acc[i][4], acc[i][5], acc[i][6], acc[i][7]);
    }
}

// ---------------- reduce partials (+optional bias) --------------------------
__global__ __launch_bounds__(256) void reduce_add(float* __restrict__ out,
    const float* __restrict__ parts, const float* __restrict__ bias,
    int nsplit, int MN, int N)
{
    int i = (blockIdx.x * 256 + threadIdx.x) << 2;
    if (i >= MN) return;
    float4 acc = *(const float4*)(parts + i);
    for (int sp = 1; sp < nsplit; ++sp) {
        float4 p = *(const float4*)(parts + (size_t)sp * MN + i);
        acc.x += p.x; acc.y += p.y; acc.z += p.z; acc.w += p.w;
    }
    if (bias) {
        float4 b = *(const float4*)(bias + (i & (N - 1)));
        acc.x += b.x; acc.y += b.y; acc.z += b.z; acc.w += b.w;
    }
    *(float4*)(out + i) = acc;
}

extern "C" void kernel_launch(void* const* d_in, const int* in_sizes, int n_in,
                              void* d_out, int out_size, void* d_ws, size_t ws_size,
                              hipStream_t stream)
{
    const float* x    = (const float*)d_in[0];
    const float* vec  = (const float*)d_in[1];
    const float* Wqkv = (const float*)d_in[2];
    const float* bqkv = (const float*)d_in[3];
    const float* Wb   = (const float*)d_in[4];
    const float* bb   = (const float*)d_in[5];
    const float* Wout = (const float*)d_in[6];
    const float* bout = (const float*)d_in[7];
    float* out = (float*)d_out;

    char* ws = (char*)d_ws;
    float*          qkv   = (float*)(ws);                      // 12,582,912
    __hip_bfloat16* sbuf  = (__hip_bfloat16*)(ws + 12582912);  // 67,108,864
    float*          mbuf  = (float*)(ws + 79691776);           //     65,536
    float*          izb   = (float*)(ws + 79757312);           //     65,536
    float*          ybuf  = (float*)(ws + 79822848);           //  4,194,304
    float*          parts = (float*)(ws + 84017152);           // 16,777,216

    gemm_f32<<<dim3(24, 32), 256, 0, stream>>>(x, Wqkv, bqkv, qkv, NT, QKV_LD, EMBD);
    scores_kernel<<<dim3(32, 32, 8), 256, 0, stream>>>(qkv, sbuf);
    softmax_stats<<<NT * NH, 256, 0, stream>>>(sbuf, mbuf, izb);
    bias_kernel<<<2080, 256, 0, stream>>>(sbuf, vec, Wb, bb, mbuf, izb);
    attnv_split<<<dim3(32, 8, 4), 256, 0, stream>>>(sbuf, qkv, parts);
    reduce_add<<<1024, 256, 0, stream>>>(ybuf, parts, nullptr, 4, NT * EMBD, EMBD);
    gemm_f32_part<<<dim3(8, 32, 4), 256, 0, stream>>>(ybuf, Wout, parts, NT, EMBD, 128);
    reduce_add<<<1024, 256, 0, stream>>>(out, parts, bout, 4, NT * EMBD, EMBD);
}

// Round 4
// 297.003 us; speedup vs baseline: 2.1321x; 1.1928x over previous
//
#include <hip/hip_runtime.h>
#include <hip/hip_bf16.h>
#include <math.h>

#define NT 2048
#define EMBD 512
#define NH 8
#define QKV_LD 1536

typedef unsigned short u16;
typedef __attribute__((ext_vector_type(8))) short short8;
typedef __attribute__((ext_vector_type(4))) float v4f;

static __device__ __forceinline__ float bf2f(unsigned int u) {
    union { unsigned int i; float f; } c; c.i = u << 16; return c.f;
}
static __device__ __forceinline__ void unpack8(uint4 r, float* f) {
    f[0] = bf2f(r.x & 0xffffu); f[1] = bf2f(r.x >> 16);
    f[2] = bf2f(r.y & 0xffffu); f[3] = bf2f(r.y >> 16);
    f[4] = bf2f(r.z & 0xffffu); f[5] = bf2f(r.z >> 16);
    f[6] = bf2f(r.w & 0xffffu); f[7] = bf2f(r.w >> 16);
}
static __device__ __forceinline__ void unpack4(uint2 r, float* f) {
    f[0] = bf2f(r.x & 0xffffu); f[1] = bf2f(r.x >> 16);
    f[2] = bf2f(r.y & 0xffffu); f[3] = bf2f(r.y >> 16);
}
static __device__ __forceinline__ unsigned int f2bf(float x) {   // RNE
    union { float f; unsigned int u; } c; c.f = x;
    return (c.u + 0x7fffu + ((c.u >> 16) & 1u)) >> 16;
}

// ------- qkv GEMM: f32 compute, bf16 output. C = x @ Wqkv + b -------------
__global__ __launch_bounds__(256) void gemm_qkv(const float* __restrict__ A,
    const float* __restrict__ B, const float* __restrict__ bias,
    u16* __restrict__ Cb, int M, int N, int K)
{
    __shared__ float As[16][68];
    __shared__ float Bs[16][68];
    const int n0 = blockIdx.x << 6, m0 = blockIdx.y << 6;
    const int t = threadIdx.x, tx = t & 15, ty = t >> 4;
    float acc[4][4] = {};
    for (int kb = 0; kb < K; kb += 16) {
#pragma unroll
        for (int l = 0; l < 4; ++l) {
            int e = t + (l << 8);
            int mm = e >> 4, kk = e & 15;
            As[kk][mm] = A[(size_t)(m0 + mm) * K + kb + kk];
        }
#pragma unroll
        for (int l = 0; l < 4; ++l) {
            int e = t + (l << 8);
            int kk = e >> 6, nn = e & 63;
            Bs[kk][nn] = B[(size_t)(kb + kk) * N + n0 + nn];
        }
        __syncthreads();
#pragma unroll
        for (int kk = 0; kk < 16; ++kk) {
            float a[4], b[4];
#pragma unroll
            for (int i = 0; i < 4; ++i) a[i] = As[kk][(ty << 2) + i];
#pragma unroll
            for (int j = 0; j < 4; ++j) b[j] = Bs[kk][(tx << 2) + j];
#pragma unroll
            for (int i = 0; i < 4; ++i)
#pragma unroll
                for (int j = 0; j < 4; ++j)
                    acc[i][j] = fmaf(a[i], b[j], acc[i][j]);
        }
        __syncthreads();
    }
#pragma unroll
    for (int i = 0; i < 4; ++i) {
        int m = m0 + (ty << 2) + i;
        unsigned int o[4];
#pragma unroll
        for (int j = 0; j < 4; ++j)
            o[j] = f2bf(acc[i][j] + bias[n0 + (tx << 2) + j]);
        uint2 w; w.x = o[0] | (o[1] << 16); w.y = o[2] | (o[3] << 16);
        *(uint2*)(Cb + (size_t)m * N + n0 + (tx << 2)) = w;
    }
}

// ------- V transpose: Vt[h][t][k] <- qkv[k][h*192+128+t] ------------------
__global__ __launch_bounds__(256) void transpose_v(const u16* __restrict__ qkvb,
                                                   u16* __restrict__ Vt)
{
    __shared__ u16 tile[64][72];
    const int h = blockIdx.y, k0 = blockIdx.x << 6;
    const int t = threadIdx.x;
    {
        int r = t >> 2, cg = (t & 3) << 4;
        const u16* src = qkvb + (size_t)(k0 + r) * QKV_LD + h * 192 + 128 + cg;
        *(uint4*)&tile[r][cg]     = *(const uint4*)src;
        *(uint4*)&tile[r][cg + 8] = *(const uint4*)(src + 8);
    }
    __syncthreads();
    {
        int c = t >> 2, kg = (t & 3) << 4;
        u16 tmp[16];
#pragma unroll
        for (int j = 0; j < 16; ++j) tmp[j] = tile[kg + j][c];
        u16* dst = Vt + ((size_t)h * 64 + c) * NT + k0 + kg;
        *(uint4*)dst       = *(uint4*)&tmp[0];
        *(uint4*)(dst + 8) = *(uint4*)&tmp[8];
    }
}

// ------- scores: s[h][q][k] = (Q·K)/8 via bf16 MFMA, frags from global ----
__global__ __launch_bounds__(256) void scores_mfma(const u16* __restrict__ qkvb,
                                                   u16* __restrict__ s)
{
    const int h = blockIdx.z;
    const int k0 = blockIdx.x << 7;
    const int q0 = (blockIdx.y << 7) + ((threadIdx.x >> 6) << 5);
    const int lane = threadIdx.x & 63;
    const int fr = lane & 15;            // frag row (m or n)
    const int kd = (lane >> 4) << 3;     // frag k offset

    const u16* qbase = qkvb + (size_t)(q0 + fr) * QKV_LD + h * 192 + kd;
    const u16* kbase = qkvb + (size_t)(k0 + fr) * QKV_LD + h * 192 + 64 + kd;

    short8 aq[2][2];
    aq[0][0] = *(const short8*)(qbase);
    aq[0][1] = *(const short8*)(qbase + 32);
    aq[1][0] = *(const short8*)(qbase + (size_t)16 * QKV_LD);
    aq[1][1] = *(const short8*)(qbase + (size_t)16 * QKV_LD + 32);

    v4f acc[2][8] = {};
#pragma unroll
    for (int nt = 0; nt < 8; ++nt) {
        short8 b0 = *(const short8*)(kbase + (size_t)nt * 16 * QKV_LD);
        short8 b1 = *(const short8*)(kbase + (size_t)nt * 16 * QKV_LD + 32);
        acc[0][nt] = __builtin_amdgcn_mfma_f32_16x16x32_bf16(aq[0][0], b0, acc[0][nt], 0, 0, 0);
        acc[0][nt] = __builtin_amdgcn_mfma_f32_16x16x32_bf16(aq[0][1], b1, acc[0][nt], 0, 0, 0);
        acc[1][nt] = __builtin_amdgcn_mfma_f32_16x16x32_bf16(aq[1][0], b0, acc[1][nt], 0, 0, 0);
        acc[1][nt] = __builtin_amdgcn_mfma_f32_16x16x32_bf16(aq[1][1], b1, acc[1][nt], 0, 0, 0);
    }
    const int qr = (lane >> 4) << 2;     // C/D: row=(lane>>4)*4+reg, col=lane&15
#pragma unroll
    for (int i = 0; i < 2; ++i)
#pragma unroll
        for (int nt = 0; nt < 8; ++nt)
#pragma unroll
            for (int r = 0; r < 4; ++r) {
                int q = q0 + (i << 4) + qr + r;
                int k = k0 + (nt << 4) + fr;
                s[((size_t)h * NT + q) * NT + k] = (u16)f2bf(acc[i][nt][r] * 0.125f);
            }
}

// ---------------- softmax stats ---------------------------------------------
__global__ __launch_bounds__(256) void softmax_stats(const u16* __restrict__ s,
                                                     float* __restrict__ mOut,
                                                     float* __restrict__ izOut)
{
    const int row = blockIdx.x;
    const int t = threadIdx.x;
    const uint4 raw = *(const uint4*)(s + (size_t)row * NT + (t << 3));
    float v[8]; unpack8(raw, v);
    float m = v[0];
#pragma unroll
    for (int i = 1; i < 8; ++i) m = fmaxf(m, v[i]);
    __shared__ float red[256];
    red[t] = m; __syncthreads();
    for (int off = 128; off > 0; off >>= 1) {
        if (t < off) red[t] = fmaxf(red[t], red[t + off]);
        __syncthreads();
    }
    m = red[0];
    __syncthreads();
    float z = 0.f;
#pragma unroll
    for (int i = 0; i < 8; ++i) z += __expf(v[i] - m);
    red[t] = z; __syncthreads();
    for (int off = 128; off > 0; off >>= 1) {
        if (t < off) red[t] += red[t + off];
        __syncthreads();
    }
    if (t == 0) { mOut[row] = m; izOut[row] = 1.0f / red[0]; }
}

// ---- attn = softmax(s)+bias: triangular 32x32 tiles (frozen numerics) ------
__global__ __launch_bounds__(256) void bias_kernel(u16* __restrict__ s,
    const float* __restrict__ vec, const float* __restrict__ Wb,
    const float* __restrict__ bb, const float* __restrict__ mbuf,
    const float* __restrict__ izbuf)
{
    __shared__ float wlds[64][8];
    __shared__ float flds[32];
    __shared__ float vql[96], vkl[96];
    __shared__ float bbl[8];
    __shared__ float bias_lds[8][32][33];

    const int t = threadIdx.x;
    int b = blockIdx.x, tq = 0, rem = 64;
    while (b >= rem) { b -= rem; ++tq; --rem; }
    const int tk = tq + b;
    const int q0 = tq << 5, k0 = tk << 5;

    for (int i = t; i < 512; i += 256) wlds[i >> 3][i & 7] = Wb[i];
    if (t < 32) flds[t] = __fdiv_rn(__fdiv_rn((float)t, 31.0f), 0.1f);
    if (t < 96) vql[t] = vec[q0 * 3 + t];
    else if (t < 192) vkl[t - 96] = vec[k0 * 3 + (t - 96)];
    else if (t < 200) bbl[t - 192] = bb[t - 192];
    __syncthreads();

    {
        const int qq = t & 31;
        const int kb = (t >> 5) << 2;
        const float a0 = vql[qq * 3], a1 = vql[qq * 3 + 1], a2 = vql[qq * 3 + 2];
        float ang[4];
#pragma unroll
        for (int j = 0; j < 4; ++j) {
            const int kk = kb + j;
            float c0 = vkl[kk * 3], c1 = vkl[kk * 3 + 1], c2 = vkl[kk * 3 + 2];
            float dot = __fadd_rn(__fadd_rn(__fmul_rn(a0, c0), __fmul_rn(a1, c1)),
                                  __fmul_rn(a2, c2));
            float dotc = fminf(fmaxf(dot, 0.0f), 1.0f);
            ang[j] = __fdiv_rn(acosf(dotc), 0.001f);
        }
        float bacc[4][8] = {};
#pragma unroll 4
        for (int i = 0; i < 32; ++i) {
            float ws[8], wc[8];
#pragma unroll
            for (int h = 0; h < 8; ++h) { ws[h] = wlds[i][h]; wc[h] = wlds[i + 32][h]; }
            const float fi = flds[i];
#pragma unroll
            for (int j = 0; j < 4; ++j) {
                float ph = __fmul_rn(fi, ang[j]);
                float rv = ph * 0.15915494309189535f;
                float rf = rv - floorf(rv);
                float si = __builtin_amdgcn_sinf(rf);
                float ci = __builtin_amdgcn_cosf(rf);
#pragma unroll
                for (int h = 0; h < 8; ++h) {
                    bacc[j][h] = fmaf(si, ws[h], bacc[j][h]);
                    bacc[j][h] = fmaf(ci, wc[h], bacc[j][h]);
                }
            }
        }
#pragma unroll
        for (int j = 0; j < 4; ++j)
#pragma unroll
            for (int h = 0; h < 8; ++h)
                bias_lds[h][qq][kb + j] = bacc[j][h];
    }
    __syncthreads();

    const int r = t >> 3;
    const int cg = (t & 7) << 2;
    {
        const int q = q0 + r;
#pragma unroll
        for (int h = 0; h < 8; ++h) {
            const float m = mbuf[h * NT + q], iz = izbuf[h * NT + q], bv = bbl[h];
            const size_t base = ((size_t)h * NT + q) * NT + k0 + cg;
            uint2 raw = *(const uint2*)(s + base);
            float v[4]; unpack4(raw, v);
            unsigned int o[4];
#pragma unroll
            for (int j = 0; j < 4; ++j) {
                float val = __expf(v[j] - m) * iz + bias_lds[h][r][cg + j] + bv;
                o[j] = f2bf(val);
            }
            uint2 w; w.x = o[0] | (o[1] << 16); w.y = o[2] | (o[3] << 16);
            *(uint2*)(s + base) = w;
        }
    }
    if (tk != tq) {
        const int q = k0 + r;
#pragma unroll
        for (int h = 0; h < 8; ++h) {
            const float m = mbuf[h * NT + q], iz = izbuf[h * NT + q], bv = bbl[h];
            const size_t base = ((size_t)h * NT + q) * NT + q0 + cg;
            uint2 raw = *(const uint2*)(s + base);
            float v[4]; unpack4(raw, v);
            unsigned int o[4];
#pragma unroll
            for (int j = 0; j < 4; ++j) {
                float val = __expf(v[j] - m) * iz + bias_lds[h][cg + j][r] + bv;
                o[j] = f2bf(val);
            }
            uint2 w; w.x = o[0] | (o[1] << 16); w.y = o[2] | (o[3] << 16);
            *(uint2*)(s + base) = w;
        }
    }
}

// ------- y_part = attn @ V via bf16 MFMA (split-K=4), frags from global ----
__global__ __launch_bounds__(256) void attnv_mfma(const u16* __restrict__ attn,
    const u16* __restrict__ Vt, float* __restrict__ ypart)
{
    const int h = blockIdx.y, z = blockIdx.z;
    const int q0 = (blockIdx.x << 6) + ((threadIdx.x >> 6) << 4);
    const int lane = threadIdx.x & 63;
    const int fr = lane & 15;
    const int kd = (lane >> 4) << 3;
    const int kbase = z << 9;

    const u16* arow  = attn + (size_t)(h * NT + q0 + fr) * NT + kbase + kd;
    const u16* vbase = Vt + ((size_t)h * 64 + fr) * NT + kbase + kd;

    v4f c[4] = {};
    for (int ks = 0; ks < 512; ks += 32) {
        short8 a = *(const short8*)(arow + ks);
#pragma unroll
        for (int nt = 0; nt < 4; ++nt) {
            short8 b = *(const short8*)(vbase + (size_t)nt * 16 * NT + ks);
            c[nt] = __builtin_amdgcn_mfma_f32_16x16x32_bf16(a, b, c[nt], 0, 0, 0);
        }
    }
    float* yp = ypart + (size_t)z * NT * EMBD;
    const int qr = (lane >> 4) << 2;
#pragma unroll
    for (int nt = 0; nt < 4; ++nt)
#pragma unroll
        for (int r = 0; r < 4; ++r)
            yp[(size_t)(q0 + qr + r) * EMBD + (h << 6) + (nt << 4) + fr] = c[nt][r];
}

// ---------------- out-proj GEMM partial (split-K, f32) ----------------------
__global__ __launch_bounds__(256) void gemm_f32_part(const float* __restrict__ A,
    const float* __restrict__ B, float* __restrict__ Cpart,
    int M, int N, int KS)
{
    __shared__ float As[16][68];
    __shared__ float Bs[16][68];
    const int n0 = blockIdx.x << 6, m0 = blockIdx.y << 6;
    const int kstart = blockIdx.z * KS;
    const int K = 512;
    const int t = threadIdx.x, tx = t & 15, ty = t >> 4;
    float acc[4][4] = {};
    for (int kb = kstart; kb < kstart + KS; kb += 16) {
#pragma unroll
        for (int l = 0; l < 4; ++l) {
            int e = t + (l << 8);
            int mm = e >> 4, kk = e & 15;
            As[kk][mm] = A[(size_t)(m0 + mm) * K + kb + kk];
        }
#pragma unroll
        for (int l = 0; l < 4; ++l) {
            int e = t + (l << 8);
            int kk = e >> 6, nn = e & 63;
            Bs[kk][nn] = B[(size_t)(kb + kk) * N + n0 + nn];
        }
        __syncthreads();
#pragma unroll
        for (int kk = 0; kk < 16; ++kk) {
            float a[4], b[4];
#pragma unroll
            for (int i = 0; i < 4; ++i) a[i] = As[kk][(ty << 2) + i];
#pragma unroll
            for (int j = 0; j < 4; ++j) b[j] = Bs[kk][(tx << 2) + j];
#pragma unroll
            for (int i = 0; i < 4; ++i)
#pragma unroll
                for (int j = 0; j < 4; ++j)
                    acc[i][j] = fmaf(a[i], b[j], acc[i][j]);
        }
        __syncthreads();
    }
    float* Cz = Cpart + (size_t)blockIdx.z * M * N;
#pragma unroll
    for (int i = 0; i < 4; ++i) {
        int m = m0 + (ty << 2) + i;
#pragma unroll
        for (int j = 0; j < 4; ++j) {
            int n = n0 + (tx << 2) + j;
            Cz[(size_t)m * N + n] = acc[i][j];
        }
    }
}

// ---------------- reduce partials (+optional bias) --------------------------
__global__ __launch_bounds__(256) void reduce_add(float* __restrict__ out,
    const float* __restrict__ parts, const float* __restrict__ bias,
    int nsplit, int MN, int N)
{
    int i = (blockIdx.x * 256 + threadIdx.x) << 2;
    if (i >= MN) return;
    float4 acc = *(const float4*)(parts + i);
    for (int sp = 1; sp < nsplit; ++sp) {
        float4 p = *(const float4*)(parts + (size_t)sp * MN + i);
        acc.x += p.x; acc.y += p.y; acc.z += p.z; acc.w += p.w;
    }
    if (bias) {
        float4 b = *(const float4*)(bias + (i & (N - 1)));
        acc.x += b.x; acc.y += b.y; acc.z += b.z; acc.w += b.w;
    }
    *(float4*)(out + i) = acc;
}

extern "C" void kernel_launch(void* const* d_in, const int* in_sizes, int n_in,
                              void* d_out, int out_size, void* d_ws, size_t ws_size,
                              hipStream_t stream)
{
    const float* x    = (const float*)d_in[0];
    const float* vec  = (const float*)d_in[1];
    const float* Wqkv = (const float*)d_in[2];
    const float* bqkv = (const float*)d_in[3];
    const float* Wb   = (const float*)d_in[4];
    const float* bb   = (const float*)d_in[5];
    const float* Wout = (const float*)d_in[6];
    const float* bout = (const float*)d_in[7];
    float* out = (float*)d_out;

    char* ws = (char*)d_ws;
    u16*   qkvb  = (u16*)(ws);                      //  6,291,456
    u16*   sbuf  = (u16*)(ws + 6291456);            // 67,108,864
    u16*   Vt    = (u16*)(ws + 73400320);           //  2,097,152
    float* mbuf  = (float*)(ws + 75497472);         //     65,536
    float* izb   = (float*)(ws + 75563008);         //     65,536
    float* ybuf  = (float*)(ws + 75628544);         //  4,194,304
    float* parts = (float*)(ws + 79822848);         // 16,777,216
    // total: 96,600,064 B

    gemm_qkv<<<dim3(24, 32), 256, 0, stream>>>(x, Wqkv, bqkv, qkvb, NT, QKV_LD, EMBD);
    transpose_v<<<dim3(32, 8), 256, 0, stream>>>(qkvb, Vt);
    scores_mfma<<<dim3(16, 16, 8), 256, 0, stream>>>(qkvb, sbuf);
    softmax_stats<<<NT * NH, 256, 0, stream>>>(sbuf, mbuf, izb);
    bias_kernel<<<2080, 256, 0, stream>>>(sbuf, vec, Wb, bb, mbuf, izb);
    attnv_mfma<<<dim3(32, 8, 4), 256, 0, stream>>>(sbuf, Vt, parts);
    reduce_add<<<1024, 256, 0, stream>>>(ybuf, parts, nullptr, 4, NT * EMBD, EMBD);
    gemm_f32_part<<<dim3(8, 32, 4), 256, 0, stream>>>(ybuf, Wout, parts, NT, EMBD, 128);
    reduce_add<<<1024, 256, 0, stream>>>(out, parts, bout, 4, NT * EMBD, EMBD);
}

// Round 5
// 283.553 us; speedup vs baseline: 2.2332x; 1.0474x over previous
//
#include <hip/hip_runtime.h>
#include <hip/hip_bf16.h>
#include <math.h>

#define NT 2048
#define EMBD 512
#define NH 8
#define QKV_LD 1536

typedef unsigned short u16;
typedef __attribute__((ext_vector_type(8))) short short8;
typedef __attribute__((ext_vector_type(4))) float v4f;

static __device__ __forceinline__ float bf2f(unsigned int u) {
    union { unsigned int i; float f; } c; c.i = u << 16; return c.f;
}
static __device__ __forceinline__ void unpack8(uint4 r, float* f) {
    f[0] = bf2f(r.x & 0xffffu); f[1] = bf2f(r.x >> 16);
    f[2] = bf2f(r.y & 0xffffu); f[3] = bf2f(r.y >> 16);
    f[4] = bf2f(r.z & 0xffffu); f[5] = bf2f(r.z >> 16);
    f[6] = bf2f(r.w & 0xffffu); f[7] = bf2f(r.w >> 16);
}
static __device__ __forceinline__ void unpack4(uint2 r, float* f) {
    f[0] = bf2f(r.x & 0xffffu); f[1] = bf2f(r.x >> 16);
    f[2] = bf2f(r.y & 0xffffu); f[3] = bf2f(r.y >> 16);
}
static __device__ __forceinline__ unsigned int f2bf(float x) {   // RNE
    union { float f; unsigned int u; } c; c.f = x;
    return (c.u + 0x7fffu + ((c.u >> 16) & 1u)) >> 16;
}

// ------- split x into bf16 hi/lo --------------------------------------------
__global__ __launch_bounds__(256) void split_x(const float* __restrict__ x,
    u16* __restrict__ xh, u16* __restrict__ xl)
{
    int i = (blockIdx.x * 256 + threadIdx.x) << 2;
    float4 v = *(const float4*)(x + i);
    float f[4] = {v.x, v.y, v.z, v.w};
    unsigned int hi[4], lo[4];
#pragma unroll
    for (int j = 0; j < 4; ++j) {
        hi[j] = f2bf(f[j]);
        lo[j] = f2bf(f[j] - bf2f(hi[j]));
    }
    uint2 wh; wh.x = hi[0] | (hi[1] << 16); wh.y = hi[2] | (hi[3] << 16);
    uint2 wl; wl.x = lo[0] | (lo[1] << 16); wl.y = lo[2] | (lo[3] << 16);
    *(uint2*)(xh + i) = wh;
    *(uint2*)(xl + i) = wl;
}

// ------- split+transpose Wqkv: Wt[n][k] bf16 hi/lo --------------------------
__global__ __launch_bounds__(256) void split_wt(const float* __restrict__ W,
    u16* __restrict__ wth, u16* __restrict__ wtl)
{
    __shared__ float tile[64][65];
    const int n0 = blockIdx.x << 6, k0 = blockIdx.y << 6;
    const int t = threadIdx.x;
    const int r = t >> 2, c4 = (t & 3) << 4;
#pragma unroll
    for (int j = 0; j < 4; ++j)
        *(float4*)&tile[r][c4 + (j << 2)] =
            *(const float4*)(W + (size_t)(k0 + r) * QKV_LD + n0 + c4 + (j << 2));
    __syncthreads();
    const int n_l = t >> 2;
    u16 th[16], tl[16];
#pragma unroll
    for (int j = 0; j < 16; ++j) {
        float f = tile[c4 + j][n_l];
        unsigned int h = f2bf(f);
        th[j] = (u16)h;
        tl[j] = (u16)f2bf(f - bf2f(h));
    }
    u16* dh = wth + (size_t)(n0 + n_l) * EMBD + k0 + c4;
    u16* dl = wtl + (size_t)(n0 + n_l) * EMBD + k0 + c4;
    *(uint4*)dh       = *(uint4*)&th[0];
    *(uint4*)(dh + 8) = *(uint4*)&th[8];
    *(uint4*)dl       = *(uint4*)&tl[0];
    *(uint4*)(dl + 8) = *(uint4*)&tl[8];
}

// ------- qkv = x @ Wqkv + b via split-precision bf16 MFMA -------------------
__global__ __launch_bounds__(256) void gemm_qkv_mfma(const u16* __restrict__ xh,
    const u16* __restrict__ xl, const u16* __restrict__ wth,
    const u16* __restrict__ wtl, const float* __restrict__ bias,
    u16* __restrict__ qkvb)
{
    const int n0 = blockIdx.x << 6, m0 = blockIdx.y << 6;
    const int w = threadIdx.x >> 6, lane = threadIdx.x & 63;
    const int wm = w >> 1, wn = w & 1;
    const int fr = lane & 15, kd = (lane >> 4) << 3;

    const u16* ah0 = xh + (size_t)(m0 + wm * 32 + fr) * EMBD + kd;
    const u16* al0 = xl + (size_t)(m0 + wm * 32 + fr) * EMBD + kd;
    const u16* bh0 = wth + (size_t)(n0 + wn * 32 + fr) * EMBD + kd;
    const u16* bl0 = wtl + (size_t)(n0 + wn * 32 + fr) * EMBD + kd;

    v4f acc[2][2] = {};
    for (int kc = 0; kc < EMBD; kc += 32) {
        short8 a_h[2], a_l[2], b_h[2], b_l[2];
#pragma unroll
        for (int im = 0; im < 2; ++im) {
            a_h[im] = *(const short8*)(ah0 + (size_t)im * 16 * EMBD + kc);
            a_l[im] = *(const short8*)(al0 + (size_t)im * 16 * EMBD + kc);
        }
#pragma unroll
        for (int in = 0; in < 2; ++in) {
            b_h[in] = *(const short8*)(bh0 + (size_t)in * 16 * EMBD + kc);
            b_l[in] = *(const short8*)(bl0 + (size_t)in * 16 * EMBD + kc);
        }
#pragma unroll
        for (int im = 0; im < 2; ++im)
#pragma unroll
            for (int in = 0; in < 2; ++in) {
                acc[im][in] = __builtin_amdgcn_mfma_f32_16x16x32_bf16(a_h[im], b_h[in], acc[im][in], 0, 0, 0);
                acc[im][in] = __builtin_amdgcn_mfma_f32_16x16x32_bf16(a_h[im], b_l[in], acc[im][in], 0, 0, 0);
                acc[im][in] = __builtin_amdgcn_mfma_f32_16x16x32_bf16(a_l[im], b_h[in], acc[im][in], 0, 0, 0);
            }
    }
    const int qr = (lane >> 4) << 2;
#pragma unroll
    for (int im = 0; im < 2; ++im)
#pragma unroll
        for (int in = 0; in < 2; ++in) {
            int n = n0 + wn * 32 + in * 16 + fr;
            float bv = bias[n];
#pragma unroll
            for (int r = 0; r < 4; ++r) {
                int m = m0 + wm * 32 + im * 16 + qr + r;
                qkvb[(size_t)m * QKV_LD + n] = (u16)f2bf(acc[im][in][r] + bv);
            }
        }
}

// ------- V transpose: Vt[h][t][k] <- qkv[k][h*192+128+t] ------------------
__global__ __launch_bounds__(256) void transpose_v(const u16* __restrict__ qkvb,
                                                   u16* __restrict__ Vt)
{
    __shared__ u16 tile[64][72];
    const int h = blockIdx.y, k0 = blockIdx.x << 6;
    const int t = threadIdx.x;
    {
        int r = t >> 2, cg = (t & 3) << 4;
        const u16* src = qkvb + (size_t)(k0 + r) * QKV_LD + h * 192 + 128 + cg;
        *(uint4*)&tile[r][cg]     = *(const uint4*)src;
        *(uint4*)&tile[r][cg + 8] = *(const uint4*)(src + 8);
    }
    __syncthreads();
    {
        int c = t >> 2, kg = (t & 3) << 4;
        u16 tmp[16];
#pragma unroll
        for (int j = 0; j < 16; ++j) tmp[j] = tile[kg + j][c];
        u16* dst = Vt + ((size_t)h * 64 + c) * NT + k0 + kg;
        *(uint4*)dst       = *(uint4*)&tmp[0];
        *(uint4*)(dst + 8) = *(uint4*)&tmp[8];
    }
}

// ------- scores: s[h][q][k] = (Q·K)/8 via bf16 MFMA, frags from global ----
__global__ __launch_bounds__(256) void scores_mfma(const u16* __restrict__ qkvb,
                                                   u16* __restrict__ s)
{
    const int h = blockIdx.z;
    const int k0 = blockIdx.x << 7;
    const int q0 = (blockIdx.y << 7) + ((threadIdx.x >> 6) << 5);
    const int lane = threadIdx.x & 63;
    const int fr = lane & 15;
    const int kd = (lane >> 4) << 3;

    const u16* qbase = qkvb + (size_t)(q0 + fr) * QKV_LD + h * 192 + kd;
    const u16* kbase = qkvb + (size_t)(k0 + fr) * QKV_LD + h * 192 + 64 + kd;

    short8 aq[2][2];
    aq[0][0] = *(const short8*)(qbase);
    aq[0][1] = *(const short8*)(qbase + 32);
    aq[1][0] = *(const short8*)(qbase + (size_t)16 * QKV_LD);
    aq[1][1] = *(const short8*)(qbase + (size_t)16 * QKV_LD + 32);

    v4f acc[2][8] = {};
#pragma unroll
    for (int nt = 0; nt < 8; ++nt) {
        short8 b0 = *(const short8*)(kbase + (size_t)nt * 16 * QKV_LD);
        short8 b1 = *(const short8*)(kbase + (size_t)nt * 16 * QKV_LD + 32);
        acc[0][nt] = __builtin_amdgcn_mfma_f32_16x16x32_bf16(aq[0][0], b0, acc[0][nt], 0, 0, 0);
        acc[0][nt] = __builtin_amdgcn_mfma_f32_16x16x32_bf16(aq[0][1], b1, acc[0][nt], 0, 0, 0);
        acc[1][nt] = __builtin_amdgcn_mfma_f32_16x16x32_bf16(aq[1][0], b0, acc[1][nt], 0, 0, 0);
        acc[1][nt] = __builtin_amdgcn_mfma_f32_16x16x32_bf16(aq[1][1], b1, acc[1][nt], 0, 0, 0);
    }
    const int qr = (lane >> 4) << 2;
#pragma unroll
    for (int i = 0; i < 2; ++i)
#pragma unroll
        for (int nt = 0; nt < 8; ++nt)
#pragma unroll
            for (int r = 0; r < 4; ++r) {
                int q = q0 + (i << 4) + qr + r;
                int k = k0 + (nt << 4) + fr;
                s[((size_t)h * NT + q) * NT + k] = (u16)f2bf(acc[i][nt][r] * 0.125f);
            }
}

// ---------------- softmax stats ---------------------------------------------
__global__ __launch_bounds__(256) void softmax_stats(const u16* __restrict__ s,
                                                     float* __restrict__ mOut,
                                                     float* __restrict__ izOut)
{
    const int row = blockIdx.x;
    const int t = threadIdx.x;
    const uint4 raw = *(const uint4*)(s + (size_t)row * NT + (t << 3));
    float v[8]; unpack8(raw, v);
    float m = v[0];
#pragma unroll
    for (int i = 1; i < 8; ++i) m = fmaxf(m, v[i]);
    __shared__ float red[256];
    red[t] = m; __syncthreads();
    for (int off = 128; off > 0; off >>= 1) {
        if (t < off) red[t] = fmaxf(red[t], red[t + off]);
        __syncthreads();
    }
    m = red[0];
    __syncthreads();
    float z = 0.f;
#pragma unroll
    for (int i = 0; i < 8; ++i) z += __expf(v[i] - m);
    red[t] = z; __syncthreads();
    for (int off = 128; off > 0; off >>= 1) {
        if (t < off) red[t] += red[t + off];
        __syncthreads();
    }
    if (t == 0) { mOut[row] = m; izOut[row] = 1.0f / red[0]; }
}

// ---- attn = softmax(s)+bias: triangle tiles, MFMA head-projection ----------
// Angle/phase/sincos numerics FROZEN (bit-identical to R3). Only the
// Σ_i feature·Wb accumulation moved to bf16 MFMA.
__global__ __launch_bounds__(256) void bias_kernel(u16* __restrict__ s,
    const float* __restrict__ vec, const float* __restrict__ Wb,
    const float* __restrict__ bb, const float* __restrict__ mbuf,
    const float* __restrict__ izbuf)
{
    __shared__ float flds[32];
    __shared__ float vql[96], vkl[96];
    __shared__ float bbl[8];
    __shared__ float ang_lds[1024];
    __shared__ float bias_lds[1024][8];

    const int t = threadIdx.x;
    int b = blockIdx.x, tq = 0, rem = 64;
    while (b >= rem) { b -= rem; ++tq; --rem; }
    const int tk = tq + b;
    const int q0 = tq << 5, k0 = tk << 5;

    if (t < 32) flds[t] = __fdiv_rn(__fdiv_rn((float)t, 31.0f), 0.1f);
    else if (t >= 32 && t < 128) vql[t - 32] = vec[q0 * 3 + (t - 32)];
    else if (t < 224) vkl[t - 128] = vec[k0 * 3 + (t - 128)];
    else if (t < 232) bbl[t - 224] = bb[t - 224];
    __syncthreads();

    // phase 1a: angles for all 1024 pairs (frozen numerics)
    {
        const int qq = t & 31, kb = (t >> 5) << 2;
        const float a0 = vql[qq * 3], a1 = vql[qq * 3 + 1], a2 = vql[qq * 3 + 2];
#pragma unroll
        for (int j = 0; j < 4; ++j) {
            const int kk = kb + j;
            float c0 = vkl[kk * 3], c1 = vkl[kk * 3 + 1], c2 = vkl[kk * 3 + 2];
            float dot = __fadd_rn(__fadd_rn(__fmul_rn(a0, c0), __fmul_rn(a1, c1)),
                                  __fmul_rn(a2, c2));
            float dotc = fminf(fmaxf(dot, 0.0f), 1.0f);
            ang_lds[(qq << 5) + kk] = __fdiv_rn(acosf(dotc), 0.001f);
        }
    }
    __syncthreads();

    // phase 1b: features (sin|cos) -> MFMA projection onto 8 heads
    {
        const int w = t >> 6, lane = t & 63;
        const int fr = lane & 15, kd = (lane >> 4) << 3, qr = (lane >> 4) << 2;
        short8 BS, BC;
#pragma unroll
        for (int j = 0; j < 8; ++j) {
            float ws = (fr < 8) ? Wb[(kd + j) * 8 + fr] : 0.0f;
            float wc = (fr < 8) ? Wb[(32 + kd + j) * 8 + fr] : 0.0f;
            BS[j] = (short)f2bf(ws);
            BC[j] = (short)f2bf(wc);
        }
        for (int tt = w; tt < 64; tt += 4) {
            float ang = ang_lds[(tt << 4) + fr];
            short8 AS, AC;
#pragma unroll
            for (int j = 0; j < 8; ++j) {
                float ph = __fmul_rn(flds[kd + j], ang);
                float rv = ph * 0.15915494309189535f;
                float rf = rv - floorf(rv);
                AS[j] = (short)f2bf(__builtin_amdgcn_sinf(rf));
                AC[j] = (short)f2bf(__builtin_amdgcn_cosf(rf));
            }
            v4f c = {};
            c = __builtin_amdgcn_mfma_f32_16x16x32_bf16(AS, BS, c, 0, 0, 0);
            c = __builtin_amdgcn_mfma_f32_16x16x32_bf16(AC, BC, c, 0, 0, 0);
            if (fr < 8)
#pragma unroll
                for (int r = 0; r < 4; ++r)
                    bias_lds[(tt << 4) + qr + r][fr] = c[r];
        }
    }
    __syncthreads();

    // phase 2: apply softmax + bias, coalesced RMW, both orientations
    const int r = t >> 3;
    const int cg = (t & 7) << 2;
    {
        const int q = q0 + r;
#pragma unroll
        for (int h = 0; h < 8; ++h) {
            const float m = mbuf[h * NT + q], iz = izbuf[h * NT + q], bv = bbl[h];
            const size_t base = ((size_t)h * NT + q) * NT + k0 + cg;
            uint2 raw = *(const uint2*)(s + base);
            float v[4]; unpack4(raw, v);
            unsigned int o[4];
#pragma unroll
            for (int j = 0; j < 4; ++j) {
                float val = __expf(v[j] - m) * iz + bias_lds[(r << 5) + cg + j][h] + bv;
                o[j] = f2bf(val);
            }
            uint2 wv; wv.x = o[0] | (o[1] << 16); wv.y = o[2] | (o[3] << 16);
            *(uint2*)(s + base) = wv;
        }
    }
    if (tk != tq) {
        const int q = k0 + r;
#pragma unroll
        for (int h = 0; h < 8; ++h) {
            const float m = mbuf[h * NT + q], iz = izbuf[h * NT + q], bv = bbl[h];
            const size_t base = ((size_t)h * NT + q) * NT + q0 + cg;
            uint2 raw = *(const uint2*)(s + base);
            float v[4]; unpack4(raw, v);
            unsigned int o[4];
#pragma unroll
            for (int j = 0; j < 4; ++j) {
                float val = __expf(v[j] - m) * iz + bias_lds[((cg + j) << 5) + r][h] + bv;
                o[j] = f2bf(val);
            }
            uint2 wv; wv.x = o[0] | (o[1] << 16); wv.y = o[2] | (o[3] << 16);
            *(uint2*)(s + base) = wv;
        }
    }
}

// ------- y_part = attn @ V via bf16 MFMA (split-K=4), frags from global ----
__global__ __launch_bounds__(256) void attnv_mfma(const u16* __restrict__ attn,
    const u16* __restrict__ Vt, float* __restrict__ ypart)
{
    const int h = blockIdx.y, z = blockIdx.z;
    const int q0 = (blockIdx.x << 6) + ((threadIdx.x >> 6) << 4);
    const int lane = threadIdx.x & 63;
    const int fr = lane & 15;
    const int kd = (lane >> 4) << 3;
    const int kbase = z << 9;

    const u16* arow  = attn + (size_t)(h * NT + q0 + fr) * NT + kbase + kd;
    const u16* vbase = Vt + ((size_t)h * 64 + fr) * NT + kbase + kd;

    v4f c[4] = {};
    for (int ks = 0; ks < 512; ks += 32) {
        short8 a = *(const short8*)(arow + ks);
#pragma unroll
        for (int nt = 0; nt < 4; ++nt) {
            short8 bv = *(const short8*)(vbase + (size_t)nt * 16 * NT + ks);
            c[nt] = __builtin_amdgcn_mfma_f32_16x16x32_bf16(a, bv, c[nt], 0, 0, 0);
        }
    }
    float* yp = ypart + (size_t)z * NT * EMBD;
    const int qr = (lane >> 4) << 2;
#pragma unroll
    for (int nt = 0; nt < 4; ++nt)
#pragma unroll
        for (int r = 0; r < 4; ++r)
            yp[(size_t)(q0 + qr + r) * EMBD + (h << 6) + (nt << 4) + fr] = c[nt][r];
}

// ---------------- out-proj GEMM partial (split-K, f32) ----------------------
__global__ __launch_bounds__(256) void gemm_f32_part(const float* __restrict__ A,
    const float* __restrict__ B, float* __restrict__ Cpart,
    int M, int N, int KS)
{
    __shared__ float As[16][68];
    __shared__ float Bs[16][68];
    const int n0 = blockIdx.x << 6, m0 = blockIdx.y << 6;
    const int kstart = blockIdx.z * KS;
    const int K = 512;
    const int t = threadIdx.x, tx = t & 15, ty = t >> 4;
    float acc[4][4] = {};
    for (int kb = kstart; kb < kstart + KS; kb += 16) {
#pragma unroll
        for (int l = 0; l < 4; ++l) {
            int e = t + (l << 8);
            int mm = e >> 4, kk = e & 15;
            As[kk][mm] = A[(size_t)(m0 + mm) * K + kb + kk];
        }
#pragma unroll
        for (int l = 0; l < 4; ++l) {
            int e = t + (l << 8);
            int kk = e >> 6, nn = e & 63;
            Bs[kk][nn] = B[(size_t)(kb + kk) * N + n0 + nn];
        }
        __syncthreads();
#pragma unroll
        for (int kk = 0; kk < 16; ++kk) {
            float a[4], bvv[4];
#pragma unroll
            for (int i = 0; i < 4; ++i) a[i] = As[kk][(ty << 2) + i];
#pragma unroll
            for (int j = 0; j < 4; ++j) bvv[j] = Bs[kk][(tx << 2) + j];
#pragma unroll
            for (int i = 0; i < 4; ++i)
#pragma unroll
                for (int j = 0; j < 4; ++j)
                    acc[i][j] = fmaf(a[i], bvv[j], acc[i][j]);
        }
        __syncthreads();
    }
    float* Cz = Cpart + (size_t)blockIdx.z * M * N;
#pragma unroll
    for (int i = 0; i < 4; ++i) {
        int m = m0 + (ty << 2) + i;
#pragma unroll
        for (int j = 0; j < 4; ++j) {
            int n = n0 + (tx << 2) + j;
            Cz[(size_t)m * N + n] = acc[i][j];
        }
    }
}

// ---------------- reduce partials (+optional bias) --------------------------
__global__ __launch_bounds__(256) void reduce_add(float* __restrict__ out,
    const float* __restrict__ parts, const float* __restrict__ bias,
    int nsplit, int MN, int N)
{
    int i = (blockIdx.x * 256 + threadIdx.x) << 2;
    if (i >= MN) return;
    float4 acc = *(const float4*)(parts + i);
    for (int sp = 1; sp < nsplit; ++sp) {
        float4 p = *(const float4*)(parts + (size_t)sp * MN + i);
        acc.x += p.x; acc.y += p.y; acc.z += p.z; acc.w += p.w;
    }
    if (bias) {
        float4 b = *(const float4*)(bias + (i & (N - 1)));
        acc.x += b.x; acc.y += b.y; acc.z += b.z; acc.w += b.w;
    }
    *(float4*)(out + i) = acc;
}

extern "C" void kernel_launch(void* const* d_in, const int* in_sizes, int n_in,
                              void* d_out, int out_size, void* d_ws, size_t ws_size,
                              hipStream_t stream)
{
    const float* x    = (const float*)d_in[0];
    const float* vec  = (const float*)d_in[1];
    const float* Wqkv = (const float*)d_in[2];
    const float* bqkv = (const float*)d_in[3];
    const float* Wb   = (const float*)d_in[4];
    const float* bb   = (const float*)d_in[5];
    const float* Wout = (const float*)d_in[6];
    const float* bout = (const float*)d_in[7];
    float* out = (float*)d_out;

    char* ws = (char*)d_ws;
    u16*   qkvb  = (u16*)(ws);                      //  6,291,456
    u16*   sbuf  = (u16*)(ws + 6291456);            // 67,108,864
    u16*   Vt    = (u16*)(ws + 73400320);           //  2,097,152
    float* mbuf  = (float*)(ws + 75497472);         //     65,536
    float* izb   = (float*)(ws + 75563008);         //     65,536
    float* ybuf  = (float*)(ws + 75628544);         //  4,194,304
    float* parts = (float*)(ws + 79822848);         // 16,777,216
    // transient split buffers alias the parts region (consumed before attnv)
    u16*   xh    = (u16*)(ws + 79822848);           //  2,097,152
    u16*   xl    = (u16*)(ws + 81920000);           //  2,097,152
    u16*   wth   = (u16*)(ws + 84017152);           //  1,572,864
    u16*   wtl   = (u16*)(ws + 85590016);           //  1,572,864
    // total: 96,600,064 B

    split_x<<<1024, 256, 0, stream>>>(x, xh, xl);
    split_wt<<<dim3(24, 8), 256, 0, stream>>>(Wqkv, wth, wtl);
    gemm_qkv_mfma<<<dim3(24, 32), 256, 0, stream>>>(xh, xl, wth, wtl, bqkv, qkvb);
    transpose_v<<<dim3(32, 8), 256, 0, stream>>>(qkvb, Vt);
    scores_mfma<<<dim3(16, 16, 8), 256, 0, stream>>>(qkvb, sbuf);
    softmax_stats<<<NT * NH, 256, 0, stream>>>(sbuf, mbuf, izb);
    bias_kernel<<<2080, 256, 0, stream>>>(sbuf, vec, Wb, bb, mbuf, izb);
    attnv_mfma<<<dim3(32, 8, 4), 256, 0, stream>>>(sbuf, Vt, parts);
    reduce_add<<<1024, 256, 0, stream>>>(ybuf, parts, nullptr, 4, NT * EMBD, EMBD);
    gemm_f32_part<<<dim3(8, 32, 4), 256, 0, stream>>>(ybuf, Wout, parts, NT, EMBD, 128);
    reduce_add<<<1024, 256, 0, stream>>>(out, parts, bout, 4, NT * EMBD, EMBD);
}

// Round 6
// 278.236 us; speedup vs baseline: 2.2759x; 1.0191x over previous
//
#include <hip/hip_runtime.h>
#include <hip/hip_bf16.h>
#include <math.h>

#define NT 2048
#define EMBD 512
#define NH 8
#define QKV_LD 1536

typedef unsigned short u16;
typedef __attribute__((ext_vector_type(8))) short short8;
typedef __attribute__((ext_vector_type(4))) float v4f;

static __device__ __forceinline__ float bf2f(unsigned int u) {
    union { unsigned int i; float f; } c; c.i = u << 16; return c.f;
}
static __device__ __forceinline__ void unpack8(uint4 r, float* f) {
    f[0] = bf2f(r.x & 0xffffu); f[1] = bf2f(r.x >> 16);
    f[2] = bf2f(r.y & 0xffffu); f[3] = bf2f(r.y >> 16);
    f[4] = bf2f(r.z & 0xffffu); f[5] = bf2f(r.z >> 16);
    f[6] = bf2f(r.w & 0xffffu); f[7] = bf2f(r.w >> 16);
}
static __device__ __forceinline__ void unpack4(uint2 r, float* f) {
    f[0] = bf2f(r.x & 0xffffu); f[1] = bf2f(r.x >> 16);
    f[2] = bf2f(r.y & 0xffffu); f[3] = bf2f(r.y >> 16);
}
static __device__ __forceinline__ unsigned int f2bf(float x) {   // RNE
    union { float f; unsigned int u; } c; c.f = x;
    return (c.u + 0x7fffu + ((c.u >> 16) & 1u)) >> 16;
}

// ------- split x into bf16 hi/lo --------------------------------------------
__global__ __launch_bounds__(256) void split_x(const float* __restrict__ x,
    u16* __restrict__ xh, u16* __restrict__ xl)
{
    int i = (blockIdx.x * 256 + threadIdx.x) << 2;
    float4 v = *(const float4*)(x + i);
    float f[4] = {v.x, v.y, v.z, v.w};
    unsigned int hi[4], lo[4];
#pragma unroll
    for (int j = 0; j < 4; ++j) {
        hi[j] = f2bf(f[j]);
        lo[j] = f2bf(f[j] - bf2f(hi[j]));
    }
    uint2 wh; wh.x = hi[0] | (hi[1] << 16); wh.y = hi[2] | (hi[3] << 16);
    uint2 wl; wl.x = lo[0] | (lo[1] << 16); wl.y = lo[2] | (lo[3] << 16);
    *(uint2*)(xh + i) = wh;
    *(uint2*)(xl + i) = wl;
}

// ------- split+transpose Wqkv: Wt[n][k] bf16 hi/lo --------------------------
__global__ __launch_bounds__(256) void split_wt(const float* __restrict__ W,
    u16* __restrict__ wth, u16* __restrict__ wtl)
{
    __shared__ float tile[64][65];
    const int n0 = blockIdx.x << 6, k0 = blockIdx.y << 6;
    const int t = threadIdx.x;
    const int r = t >> 2, c4 = (t & 3) << 4;
#pragma unroll
    for (int j = 0; j < 4; ++j)
        *(float4*)&tile[r][c4 + (j << 2)] =
            *(const float4*)(W + (size_t)(k0 + r) * QKV_LD + n0 + c4 + (j << 2));
    __syncthreads();
    const int n_l = t >> 2;
    u16 th[16], tl[16];
#pragma unroll
    for (int j = 0; j < 16; ++j) {
        float f = tile[c4 + j][n_l];
        unsigned int h = f2bf(f);
        th[j] = (u16)h;
        tl[j] = (u16)f2bf(f - bf2f(h));
    }
    u16* dh = wth + (size_t)(n0 + n_l) * EMBD + k0 + c4;
    u16* dl = wtl + (size_t)(n0 + n_l) * EMBD + k0 + c4;
    *(uint4*)dh       = *(uint4*)&th[0];
    *(uint4*)(dh + 8) = *(uint4*)&th[8];
    *(uint4*)dl       = *(uint4*)&tl[0];
    *(uint4*)(dl + 8) = *(uint4*)&tl[8];
}

// ------- split+transpose Wout (512x512): Wt[n][k] bf16 hi/lo ----------------
__global__ __launch_bounds__(256) void split_wout(const float* __restrict__ W,
    u16* __restrict__ wh, u16* __restrict__ wl)
{
    __shared__ float tile[64][65];
    const int n0 = blockIdx.x << 6, k0 = blockIdx.y << 6;
    const int t = threadIdx.x;
    const int r = t >> 2, c4 = (t & 3) << 4;
#pragma unroll
    for (int j = 0; j < 4; ++j)
        *(float4*)&tile[r][c4 + (j << 2)] =
            *(const float4*)(W + (size_t)(k0 + r) * EMBD + n0 + c4 + (j << 2));
    __syncthreads();
    const int n_l = t >> 2;
    u16 th[16], tl[16];
#pragma unroll
    for (int j = 0; j < 16; ++j) {
        float f = tile[c4 + j][n_l];
        unsigned int h = f2bf(f);
        th[j] = (u16)h;
        tl[j] = (u16)f2bf(f - bf2f(h));
    }
    u16* dh = wh + (size_t)(n0 + n_l) * EMBD + k0 + c4;
    u16* dl = wl + (size_t)(n0 + n_l) * EMBD + k0 + c4;
    *(uint4*)dh       = *(uint4*)&th[0];
    *(uint4*)(dh + 8) = *(uint4*)&th[8];
    *(uint4*)dl       = *(uint4*)&tl[0];
    *(uint4*)(dl + 8) = *(uint4*)&tl[8];
}

// ------- qkv = x @ Wqkv + b via split-precision bf16 MFMA -------------------
__global__ __launch_bounds__(256) void gemm_qkv_mfma(const u16* __restrict__ xh,
    const u16* __restrict__ xl, const u16* __restrict__ wth,
    const u16* __restrict__ wtl, const float* __restrict__ bias,
    u16* __restrict__ qkvb)
{
    const int n0 = blockIdx.x << 6, m0 = blockIdx.y << 6;
    const int w = threadIdx.x >> 6, lane = threadIdx.x & 63;
    const int wm = w >> 1, wn = w & 1;
    const int fr = lane & 15, kd = (lane >> 4) << 3;

    const u16* ah0 = xh + (size_t)(m0 + wm * 32 + fr) * EMBD + kd;
    const u16* al0 = xl + (size_t)(m0 + wm * 32 + fr) * EMBD + kd;
    const u16* bh0 = wth + (size_t)(n0 + wn * 32 + fr) * EMBD + kd;
    const u16* bl0 = wtl + (size_t)(n0 + wn * 32 + fr) * EMBD + kd;

    v4f acc[2][2] = {};
    for (int kc = 0; kc < EMBD; kc += 32) {
        short8 a_h[2], a_l[2], b_h[2], b_l[2];
#pragma unroll
        for (int im = 0; im < 2; ++im) {
            a_h[im] = *(const short8*)(ah0 + (size_t)im * 16 * EMBD + kc);
            a_l[im] = *(const short8*)(al0 + (size_t)im * 16 * EMBD + kc);
        }
#pragma unroll
        for (int in = 0; in < 2; ++in) {
            b_h[in] = *(const short8*)(bh0 + (size_t)in * 16 * EMBD + kc);
            b_l[in] = *(const short8*)(bl0 + (size_t)in * 16 * EMBD + kc);
        }
#pragma unroll
        for (int im = 0; im < 2; ++im)
#pragma unroll
            for (int in = 0; in < 2; ++in) {
                acc[im][in] = __builtin_amdgcn_mfma_f32_16x16x32_bf16(a_h[im], b_h[in], acc[im][in], 0, 0, 0);
                acc[im][in] = __builtin_amdgcn_mfma_f32_16x16x32_bf16(a_h[im], b_l[in], acc[im][in], 0, 0, 0);
                acc[im][in] = __builtin_amdgcn_mfma_f32_16x16x32_bf16(a_l[im], b_h[in], acc[im][in], 0, 0, 0);
            }
    }
    const int qr = (lane >> 4) << 2;
#pragma unroll
    for (int im = 0; im < 2; ++im)
#pragma unroll
        for (int in = 0; in < 2; ++in) {
            int n = n0 + wn * 32 + in * 16 + fr;
            float bv = bias[n];
#pragma unroll
            for (int r = 0; r < 4; ++r) {
                int m = m0 + wm * 32 + im * 16 + qr + r;
                qkvb[(size_t)m * QKV_LD + n] = (u16)f2bf(acc[im][in][r] + bv);
            }
        }
}

// ------- V transpose: Vt[h][t][k] <- qkv[k][h*192+128+t] ------------------
__global__ __launch_bounds__(256) void transpose_v(const u16* __restrict__ qkvb,
                                                   u16* __restrict__ Vt)
{
    __shared__ u16 tile[64][72];
    const int h = blockIdx.y, k0 = blockIdx.x << 6;
    const int t = threadIdx.x;
    {
        int r = t >> 2, cg = (t & 3) << 4;
        const u16* src = qkvb + (size_t)(k0 + r) * QKV_LD + h * 192 + 128 + cg;
        *(uint4*)&tile[r][cg]     = *(const uint4*)src;
        *(uint4*)&tile[r][cg + 8] = *(const uint4*)(src + 8);
    }
    __syncthreads();
    {
        int c = t >> 2, kg = (t & 3) << 4;
        u16 tmp[16];
#pragma unroll
        for (int j = 0; j < 16; ++j) tmp[j] = tile[kg + j][c];
        u16* dst = Vt + ((size_t)h * 64 + c) * NT + k0 + kg;
        *(uint4*)dst       = *(uint4*)&tmp[0];
        *(uint4*)(dst + 8) = *(uint4*)&tmp[8];
    }
}

// ------- scores + exp-rowsum: s = QK/8 (bf16), zbuf[h][q] += sum_k exp(s) ---
__global__ __launch_bounds__(256) void scores_mfma(const u16* __restrict__ qkvb,
                                                   u16* __restrict__ s,
                                                   float* __restrict__ zbuf)
{
    const int h = blockIdx.z;
    const int k0 = blockIdx.x << 7;
    const int q0 = (blockIdx.y << 7) + ((threadIdx.x >> 6) << 5);
    const int lane = threadIdx.x & 63;
    const int fr = lane & 15;
    const int kd = (lane >> 4) << 3;

    const u16* qbase = qkvb + (size_t)(q0 + fr) * QKV_LD + h * 192 + kd;
    const u16* kbase = qkvb + (size_t)(k0 + fr) * QKV_LD + h * 192 + 64 + kd;

    short8 aq[2][2];
    aq[0][0] = *(const short8*)(qbase);
    aq[0][1] = *(const short8*)(qbase + 32);
    aq[1][0] = *(const short8*)(qbase + (size_t)16 * QKV_LD);
    aq[1][1] = *(const short8*)(qbase + (size_t)16 * QKV_LD + 32);

    v4f acc[2][8] = {};
#pragma unroll
    for (int nt = 0; nt < 8; ++nt) {
        short8 b0 = *(const short8*)(kbase + (size_t)nt * 16 * QKV_LD);
        short8 b1 = *(const short8*)(kbase + (size_t)nt * 16 * QKV_LD + 32);
        acc[0][nt] = __builtin_amdgcn_mfma_f32_16x16x32_bf16(aq[0][0], b0, acc[0][nt], 0, 0, 0);
        acc[0][nt] = __builtin_amdgcn_mfma_f32_16x16x32_bf16(aq[0][1], b1, acc[0][nt], 0, 0, 0);
        acc[1][nt] = __builtin_amdgcn_mfma_f32_16x16x32_bf16(aq[1][0], b0, acc[1][nt], 0, 0, 0);
        acc[1][nt] = __builtin_amdgcn_mfma_f32_16x16x32_bf16(aq[1][1], b1, acc[1][nt], 0, 0, 0);
    }
    const int qr = (lane >> 4) << 2;
    // stores (bf16) — unchanged
#pragma unroll
    for (int i = 0; i < 2; ++i)
#pragma unroll
        for (int nt = 0; nt < 8; ++nt)
#pragma unroll
            for (int r = 0; r < 4; ++r) {
                int q = q0 + (i << 4) + qr + r;
                int k = k0 + (nt << 4) + fr;
                s[((size_t)h * NT + q) * NT + k] = (u16)f2bf(acc[i][nt][r] * 0.125f);
            }
    // per-row sum of exp (no max subtraction: |s| <= ~6, safe in f32)
    float es[2][4];
#pragma unroll
    for (int i = 0; i < 2; ++i)
#pragma unroll
        for (int r = 0; r < 4; ++r) {
            float sum = 0.f;
#pragma unroll
            for (int nt = 0; nt < 8; ++nt)
                sum += __expf(acc[i][nt][r] * 0.125f);
            es[i][r] = sum;
        }
#pragma unroll
    for (int off = 1; off < 16; off <<= 1)
#pragma unroll
        for (int i = 0; i < 2; ++i)
#pragma unroll
            for (int r = 0; r < 4; ++r)
                es[i][r] += __shfl_xor(es[i][r], off);
    if (fr == 0) {
#pragma unroll
        for (int i = 0; i < 2; ++i)
#pragma unroll
            for (int r = 0; r < 4; ++r)
                atomicAdd(zbuf + h * NT + q0 + (i << 4) + qr + r, es[i][r]);
    }
}

// ---- attn = softmax(s)+bias: triangle tiles, clip-compaction ---------------
// Angle/phase/sincos numerics FROZEN. ~half of all pairs have dot<=0 ->
// identical clipped angle -> one precomputed clip-bias; sincos+MFMA run only
// on compacted non-clipped pairs. bias LDS layout: head stride 1057,
// row stride 33 (conflict-free, cf. R3 measured 0 / R5's [1024][8] 4.7M).
__global__ __launch_bounds__(256) void bias_kernel(u16* __restrict__ s,
    const float* __restrict__ vec, const float* __restrict__ Wb,
    const float* __restrict__ bb, const float* __restrict__ zbuf)
{
    __shared__ float flds[32];
    __shared__ float vql[96], vkl[96];
    __shared__ float bbl[8];
    __shared__ float ang_lds[1025];
    __shared__ float biasl[8 * 1057];
    __shared__ float clipb[8];
    __shared__ unsigned char flagl[1024];
    __shared__ u16 list[1040];
    __shared__ int cnt;

    const int t = threadIdx.x;
    int b = blockIdx.x, tq = 0, rem = 64;
    while (b >= rem) { b -= rem; ++tq; --rem; }
    const int tk = tq + b;
    const int q0 = tq << 5, k0 = tk << 5;

    if (t == 0) cnt = 0;
    if (t < 32) flds[t] = __fdiv_rn(__fdiv_rn((float)t, 31.0f), 0.1f);
    else if (t < 128) vql[t - 32] = vec[q0 * 3 + (t - 32)];
    else if (t < 224) vkl[t - 128] = vec[k0 * 3 + (t - 128)];
    else if (t < 232) bbl[t - 224] = bb[t - 224];
    __syncthreads();

    // phase 1a: angles (frozen numerics) + clip flags + stream compaction
    {
        const int qq = t & 31, kb = (t >> 5) << 2;
        const int lane = t & 63;
        const float a0 = vql[qq * 3], a1 = vql[qq * 3 + 1], a2 = vql[qq * 3 + 2];
#pragma unroll
        for (int j = 0; j < 4; ++j) {
            const int kk = kb + j;
            const int p = (qq << 5) + kk;
            float c0 = vkl[kk * 3], c1 = vkl[kk * 3 + 1], c2 = vkl[kk * 3 + 2];
            float dot = __fadd_rn(__fadd_rn(__fmul_rn(a0, c0), __fmul_rn(a1, c1)),
                                  __fmul_rn(a2, c2));
            float dotc = fminf(fmaxf(dot, 0.0f), 1.0f);
            ang_lds[p] = __fdiv_rn(acosf(dotc), 0.001f);
            int live = (dot > 0.0f) ? 1 : 0;
            flagl[p] = (unsigned char)(1 - live);
            unsigned long long m = __ballot(live);
            int base = 0;
            if (lane == 0) base = atomicAdd(&cnt, __popcll(m));
            base = __shfl(base, 0);
            if (live)
                list[base + __popcll(m & ((1ull << lane) - 1ull))] = (u16)p;
        }
    }
    __syncthreads();
    if (t == 0) {
        int c = cnt;
        int padded = (c + 15) & ~15;
        for (int i = c; i < padded; ++i) list[i] = 1024;
        // runtime-opaque zero -> device acosf path, same op sequence as dot<=0
        float zero = fabsf(vql[0]) * 0.0f;
        float zc = fminf(fmaxf(zero, 0.0f), 1.0f);
        ang_lds[1024] = __fdiv_rn(acosf(zc), 0.001f);
        cnt = padded;
    }
    __syncthreads();
    const int ntiles = cnt >> 4;

    // phase 1b: sincos features -> MFMA projection, compacted pairs only
    {
        const int w = t >> 6, lane = t & 63;
        const int fr = lane & 15, kd = (lane >> 4) << 3, qr = (lane >> 4) << 2;
        short8 BS, BC;
#pragma unroll
        for (int j = 0; j < 8; ++j) {
            float ws = (fr < 8) ? Wb[(kd + j) * 8 + fr] : 0.0f;
            float wc = (fr < 8) ? Wb[(32 + kd + j) * 8 + fr] : 0.0f;
            BS[j] = (short)f2bf(ws);
            BC[j] = (short)f2bf(wc);
        }
        if (w == 0) {   // clip-representative bias (all rows = clip angle)
            float ang = ang_lds[1024];
            short8 AS, AC;
#pragma unroll
            for (int j = 0; j < 8; ++j) {
                float ph = __fmul_rn(flds[kd + j], ang);
                float rv = ph * 0.15915494309189535f;
                float rf = rv - floorf(rv);
                AS[j] = (short)f2bf(__builtin_amdgcn_sinf(rf));
                AC[j] = (short)f2bf(__builtin_amdgcn_cosf(rf));
            }
            v4f c = {};
            c = __builtin_amdgcn_mfma_f32_16x16x32_bf16(AS, BS, c, 0, 0, 0);
            c = __builtin_amdgcn_mfma_f32_16x16x32_bf16(AC, BC, c, 0, 0, 0);
            if (fr < 8) clipb[fr] = c[0];
        }
        for (int i = w; i < ntiles; i += 4) {
            float ang = ang_lds[list[(i << 4) + fr]];
            short8 AS, AC;
#pragma unroll
            for (int j = 0; j < 8; ++j) {
                float ph = __fmul_rn(flds[kd + j], ang);
                float rv = ph * 0.15915494309189535f;
                float rf = rv - floorf(rv);
                AS[j] = (short)f2bf(__builtin_amdgcn_sinf(rf));
                AC[j] = (short)f2bf(__builtin_amdgcn_cosf(rf));
            }
            v4f c = {};
            c = __builtin_amdgcn_mfma_f32_16x16x32_bf16(AS, BS, c, 0, 0, 0);
            c = __builtin_amdgcn_mfma_f32_16x16x32_bf16(AC, BC, c, 0, 0, 0);
            if (fr < 8) {
#pragma unroll
                for (int r = 0; r < 4; ++r) {
                    int p = list[(i << 4) + qr + r];
                    if (p < 1024)
                        biasl[fr * 1057 + (p >> 5) * 33 + (p & 31)] = c[r];
                }
            }
        }
    }
    __syncthreads();

    // phase 2: apply softmax + bias, coalesced RMW, both orientations
    const int r = t >> 3;
    const int cg = (t & 7) << 2;
    {
        const int q = q0 + r;
#pragma unroll
        for (int h = 0; h < 8; ++h) {
            const float iz = 1.0f / zbuf[h * NT + q];
            const float bv = bbl[h];
            const size_t base = ((size_t)h * NT + q) * NT + k0 + cg;
            uint2 raw = *(const uint2*)(s + base);
            float v[4]; unpack4(raw, v);
            unsigned int o[4];
#pragma unroll
            for (int j = 0; j < 4; ++j) {
                int p = (r << 5) + cg + j;
                float bias = flagl[p] ? clipb[h] : biasl[h * 1057 + r * 33 + cg + j];
                o[j] = f2bf(__expf(v[j]) * iz + bias + bv);
            }
            uint2 wv; wv.x = o[0] | (o[1] << 16); wv.y = o[2] | (o[3] << 16);
            *(uint2*)(s + base) = wv;
        }
    }
    if (tk != tq) {
        const int q = k0 + r;
#pragma unroll
        for (int h = 0; h < 8; ++h) {
            const float iz = 1.0f / zbuf[h * NT + q];
            const float bv = bbl[h];
            const size_t base = ((size_t)h * NT + q) * NT + q0 + cg;
            uint2 raw = *(const uint2*)(s + base);
            float v[4]; unpack4(raw, v);
            unsigned int o[4];
#pragma unroll
            for (int j = 0; j < 4; ++j) {
                int p = ((cg + j) << 5) + r;
                float bias = flagl[p] ? clipb[h] : biasl[h * 1057 + (cg + j) * 33 + r];
                o[j] = f2bf(__expf(v[j]) * iz + bias + bv);
            }
            uint2 wv; wv.x = o[0] | (o[1] << 16); wv.y = o[2] | (o[3] << 16);
            *(uint2*)(s + base) = wv;
        }
    }
}

// ------- y_part = attn @ V via bf16 MFMA (split-K=4), frags from global ----
__global__ __launch_bounds__(256) void attnv_mfma(const u16* __restrict__ attn,
    const u16* __restrict__ Vt, float* __restrict__ ypart)
{
    const int h = blockIdx.y, z = blockIdx.z;
    const int q0 = (blockIdx.x << 6) + ((threadIdx.x >> 6) << 4);
    const int lane = threadIdx.x & 63;
    const int fr = lane & 15;
    const int kd = (lane >> 4) << 3;
    const int kbase = z << 9;

    const u16* arow  = attn + (size_t)(h * NT + q0 + fr) * NT + kbase + kd;
    const u16* vbase = Vt + ((size_t)h * 64 + fr) * NT + kbase + kd;

    v4f c[4] = {};
    for (int ks = 0; ks < 512; ks += 32) {
        short8 a = *(const short8*)(arow + ks);
#pragma unroll
        for (int nt = 0; nt < 4; ++nt) {
            short8 bv = *(const short8*)(vbase + (size_t)nt * 16 * NT + ks);
            c[nt] = __builtin_amdgcn_mfma_f32_16x16x32_bf16(a, bv, c[nt], 0, 0, 0);
        }
    }
    float* yp = ypart + (size_t)z * NT * EMBD;
    const int qr = (lane >> 4) << 2;
#pragma unroll
    for (int nt = 0; nt < 4; ++nt)
#pragma unroll
        for (int r = 0; r < 4; ++r)
            yp[(size_t)(q0 + qr + r) * EMBD + (h << 6) + (nt << 4) + fr] = c[nt][r];
}

// ------- reduce 4 y-partials -> bf16 hi/lo ----------------------------------
__global__ __launch_bounds__(256) void reduce_y(const float* __restrict__ parts,
    u16* __restrict__ yh, u16* __restrict__ yl)
{
    const int MN = NT * EMBD;
    int i = (blockIdx.x * 256 + threadIdx.x) << 2;
    float4 acc = *(const float4*)(parts + i);
#pragma unroll
    for (int sp = 1; sp < 4; ++sp) {
        float4 p = *(const float4*)(parts + (size_t)sp * MN + i);
        acc.x += p.x; acc.y += p.y; acc.z += p.z; acc.w += p.w;
    }
    float f[4] = {acc.x, acc.y, acc.z, acc.w};
    unsigned int hi[4], lo[4];
#pragma unroll
    for (int j = 0; j < 4; ++j) {
        hi[j] = f2bf(f[j]);
        lo[j] = f2bf(f[j] - bf2f(hi[j]));
    }
    uint2 wh; wh.x = hi[0] | (hi[1] << 16); wh.y = hi[2] | (hi[3] << 16);
    uint2 wl; wl.x = lo[0] | (lo[1] << 16); wl.y = lo[2] | (lo[3] << 16);
    *(uint2*)(yh + i) = wh;
    *(uint2*)(yl + i) = wl;
}

// ------- out = y @ Wout + bout via split-precision bf16 MFMA ----------------
__global__ __launch_bounds__(256) void gemm_out_mfma(const u16* __restrict__ yh,
    const u16* __restrict__ yl, const u16* __restrict__ wh,
    const u16* __restrict__ wl, const float* __restrict__ bias,
    float* __restrict__ out)
{
    const int n0 = blockIdx.x << 6, m0 = blockIdx.y << 6;
    const int w = threadIdx.x >> 6, lane = threadIdx.x & 63;
    const int wm = w >> 1, wn = w & 1;
    const int fr = lane & 15, kd = (lane >> 4) << 3;

    const u16* ah0 = yh + (size_t)(m0 + wm * 32 + fr) * EMBD + kd;
    const u16* al0 = yl + (size_t)(m0 + wm * 32 + fr) * EMBD + kd;
    const u16* bh0 = wh + (size_t)(n0 + wn * 32 + fr) * EMBD + kd;
    const u16* bl0 = wl + (size_t)(n0 + wn * 32 + fr) * EMBD + kd;

    v4f acc[2][2] = {};
    for (int kc = 0; kc < EMBD; kc += 32) {
        short8 a_h[2], a_l[2], b_h[2], b_l[2];
#pragma unroll
        for (int im = 0; im < 2; ++im) {
            a_h[im] = *(const short8*)(ah0 + (size_t)im * 16 * EMBD + kc);
            a_l[im] = *(const short8*)(al0 + (size_t)im * 16 * EMBD + kc);
        }
#pragma unroll
        for (int in = 0; in < 2; ++in) {
            b_h[in] = *(const short8*)(bh0 + (size_t)in * 16 * EMBD + kc);
            b_l[in] = *(const short8*)(bl0 + (size_t)in * 16 * EMBD + kc);
        }
#pragma unroll
        for (int im = 0; im < 2; ++im)
#pragma unroll
            for (int in = 0; in < 2; ++in) {
                acc[im][in] = __builtin_amdgcn_mfma_f32_16x16x32_bf16(a_h[im], b_h[in], acc[im][in], 0, 0, 0);
                acc[im][in] = __builtin_amdgcn_mfma_f32_16x16x32_bf16(a_h[im], b_l[in], acc[im][in], 0, 0, 0);
                acc[im][in] = __builtin_amdgcn_mfma_f32_16x16x32_bf16(a_l[im], b_h[in], acc[im][in], 0, 0, 0);
            }
    }
    const int qr = (lane >> 4) << 2;
#pragma unroll
    for (int im = 0; im < 2; ++im)
#pragma unroll
        for (int in = 0; in < 2; ++in) {
            int n = n0 + wn * 32 + in * 16 + fr;
            float bv = bias[n];
#pragma unroll
            for (int r = 0; r < 4; ++r) {
                int m = m0 + wm * 32 + im * 16 + qr + r;
                out[(size_t)m * EMBD + n] = acc[im][in][r] + bv;
            }
        }
}

extern "C" void kernel_launch(void* const* d_in, const int* in_sizes, int n_in,
                              void* d_out, int out_size, void* d_ws, size_t ws_size,
                              hipStream_t stream)
{
    const float* x    = (const float*)d_in[0];
    const float* vec  = (const float*)d_in[1];
    const float* Wqkv = (const float*)d_in[2];
    const float* bqkv = (const float*)d_in[3];
    const float* Wb   = (const float*)d_in[4];
    const float* bb   = (const float*)d_in[5];
    const float* Wout = (const float*)d_in[6];
    const float* bout = (const float*)d_in[7];
    float* out = (float*)d_out;

    char* ws = (char*)d_ws;
    u16*   qkvb  = (u16*)(ws);                      //  6,291,456
    u16*   sbuf  = (u16*)(ws + 6291456);            // 67,108,864
    u16*   Vt    = (u16*)(ws + 73400320);           //  2,097,152
    float* zbuf  = (float*)(ws + 75497472);         //     65,536
    u16*   yh    = (u16*)(ws + 75628544);           //  2,097,152
    u16*   yl    = (u16*)(ws + 77725696);           //  2,097,152
    float* parts = (float*)(ws + 79822848);         // 16,777,216
    // transient aliases into the parts region (sequenced by launch order):
    u16*   xh    = (u16*)(ws + 79822848);           // consumed by gemm_qkv
    u16*   xl    = (u16*)(ws + 81920000);
    u16*   wth   = (u16*)(ws + 84017152);
    u16*   wtl   = (u16*)(ws + 85590016);
    u16*   woth  = (u16*)(ws + 79822848);           // written after reduce_y
    u16*   wotl  = (u16*)(ws + 80347136);
    // total: 96,600,064 B

    hipMemsetAsync(zbuf, 0, NH * NT * sizeof(float), stream);
    split_x<<<1024, 256, 0, stream>>>(x, xh, xl);
    split_wt<<<dim3(24, 8), 256, 0, stream>>>(Wqkv, wth, wtl);
    gemm_qkv_mfma<<<dim3(24, 32), 256, 0, stream>>>(xh, xl, wth, wtl, bqkv, qkvb);
    transpose_v<<<dim3(32, 8), 256, 0, stream>>>(qkvb, Vt);
    scores_mfma<<<dim3(16, 16, 8), 256, 0, stream>>>(qkvb, sbuf, zbuf);
    bias_kernel<<<2080, 256, 0, stream>>>(sbuf, vec, Wb, bb, zbuf);
    attnv_mfma<<<dim3(32, 8, 4), 256, 0, stream>>>(sbuf, Vt, parts);
    reduce_y<<<1024, 256, 0, stream>>>(parts, yh, yl);
    split_wout<<<dim3(8, 8), 256, 0, stream>>>(Wout, woth, wotl);
    gemm_out_mfma<<<dim3(8, 32), 256, 0, stream>>>(yh, yl, woth, wotl, bout, out);
}

// Round 7
// 274.568 us; speedup vs baseline: 2.3063x; 1.0134x over previous
//
#include <hip/hip_runtime.h>
#include <hip/hip_bf16.h>
#include <math.h>

#define NT 2048
#define EMBD 512
#define NH 8
#define QKV_LD 1536

typedef unsigned short u16;
typedef __attribute__((ext_vector_type(8))) short short8;
typedef __attribute__((ext_vector_type(4))) float v4f;

static __device__ __forceinline__ float bf2f(unsigned int u) {
    union { unsigned int i; float f; } c; c.i = u << 16; return c.f;
}
static __device__ __forceinline__ void unpack4(uint2 r, float* f) {
    f[0] = bf2f(r.x & 0xffffu); f[1] = bf2f(r.x >> 16);
    f[2] = bf2f(r.y & 0xffffu); f[3] = bf2f(r.y >> 16);
}
static __device__ __forceinline__ unsigned int f2bf(float x) {   // RNE
    union { float f; unsigned int u; } c; c.f = x;
    return (c.u + 0x7fffu + ((c.u >> 16) & 1u)) >> 16;
}

// ------- split x into bf16 hi/lo --------------------------------------------
__global__ __launch_bounds__(256) void split_x(const float* __restrict__ x,
    u16* __restrict__ xh, u16* __restrict__ xl)
{
    int i = (blockIdx.x * 256 + threadIdx.x) << 2;
    float4 v = *(const float4*)(x + i);
    float f[4] = {v.x, v.y, v.z, v.w};
    unsigned int hi[4], lo[4];
#pragma unroll
    for (int j = 0; j < 4; ++j) {
        hi[j] = f2bf(f[j]);
        lo[j] = f2bf(f[j] - bf2f(hi[j]));
    }
    uint2 wh; wh.x = hi[0] | (hi[1] << 16); wh.y = hi[2] | (hi[3] << 16);
    uint2 wl; wl.x = lo[0] | (lo[1] << 16); wl.y = lo[2] | (lo[3] << 16);
    *(uint2*)(xh + i) = wh;
    *(uint2*)(xl + i) = wl;
}

// ------- split+transpose W[K][N] -> Wt[n][k] bf16 hi/lo (row stride ld) -----
__global__ __launch_bounds__(256) void split_wt(const float* __restrict__ W,
    u16* __restrict__ wth, u16* __restrict__ wtl, int ld)
{
    __shared__ float tile[64][65];
    const int n0 = blockIdx.x << 6, k0 = blockIdx.y << 6;
    const int t = threadIdx.x;
    const int r = t >> 2, c4 = (t & 3) << 4;
#pragma unroll
    for (int j = 0; j < 4; ++j)
        *(float4*)&tile[r][c4 + (j << 2)] =
            *(const float4*)(W + (size_t)(k0 + r) * ld + n0 + c4 + (j << 2));
    __syncthreads();
    const int n_l = t >> 2;
    u16 th[16], tl[16];
#pragma unroll
    for (int j = 0; j < 16; ++j) {
        float f = tile[c4 + j][n_l];
        unsigned int h = f2bf(f);
        th[j] = (u16)h;
        tl[j] = (u16)f2bf(f - bf2f(h));
    }
    u16* dh = wth + (size_t)(n0 + n_l) * EMBD + k0 + c4;
    u16* dl = wtl + (size_t)(n0 + n_l) * EMBD + k0 + c4;
    *(uint4*)dh       = *(uint4*)&th[0];
    *(uint4*)(dh + 8) = *(uint4*)&th[8];
    *(uint4*)dl       = *(uint4*)&tl[0];
    *(uint4*)(dl + 8) = *(uint4*)&tl[8];
}

// ------- qkv = x @ Wqkv + b via split-precision bf16 MFMA -------------------
__global__ __launch_bounds__(256) void gemm_qkv_mfma(const u16* __restrict__ xh,
    const u16* __restrict__ xl, const u16* __restrict__ wth,
    const u16* __restrict__ wtl, const float* __restrict__ bias,
    u16* __restrict__ qkvb)
{
    const int n0 = blockIdx.x << 6, m0 = blockIdx.y << 6;
    const int w = threadIdx.x >> 6, lane = threadIdx.x & 63;
    const int wm = w >> 1, wn = w & 1;
    const int fr = lane & 15, kd = (lane >> 4) << 3;

    const u16* ah0 = xh + (size_t)(m0 + wm * 32 + fr) * EMBD + kd;
    const u16* al0 = xl + (size_t)(m0 + wm * 32 + fr) * EMBD + kd;
    const u16* bh0 = wth + (size_t)(n0 + wn * 32 + fr) * EMBD + kd;
    const u16* bl0 = wtl + (size_t)(n0 + wn * 32 + fr) * EMBD + kd;

    v4f acc[2][2] = {};
    for (int kc = 0; kc < EMBD; kc += 32) {
        short8 a_h[2], a_l[2], b_h[2], b_l[2];
#pragma unroll
        for (int im = 0; im < 2; ++im) {
            a_h[im] = *(const short8*)(ah0 + (size_t)im * 16 * EMBD + kc);
            a_l[im] = *(const short8*)(al0 + (size_t)im * 16 * EMBD + kc);
        }
#pragma unroll
        for (int in = 0; in < 2; ++in) {
            b_h[in] = *(const short8*)(bh0 + (size_t)in * 16 * EMBD + kc);
            b_l[in] = *(const short8*)(bl0 + (size_t)in * 16 * EMBD + kc);
        }
#pragma unroll
        for (int im = 0; im < 2; ++im)
#pragma unroll
            for (int in = 0; in < 2; ++in) {
                acc[im][in] = __builtin_amdgcn_mfma_f32_16x16x32_bf16(a_h[im], b_h[in], acc[im][in], 0, 0, 0);
                acc[im][in] = __builtin_amdgcn_mfma_f32_16x16x32_bf16(a_h[im], b_l[in], acc[im][in], 0, 0, 0);
                acc[im][in] = __builtin_amdgcn_mfma_f32_16x16x32_bf16(a_l[im], b_h[in], acc[im][in], 0, 0, 0);
            }
    }
    const int qr = (lane >> 4) << 2;
#pragma unroll
    for (int im = 0; im < 2; ++im)
#pragma unroll
        for (int in = 0; in < 2; ++in) {
            int n = n0 + wn * 32 + in * 16 + fr;
            float bv = bias[n];
#pragma unroll
            for (int r = 0; r < 4; ++r) {
                int m = m0 + wm * 32 + im * 16 + qr + r;
                qkvb[(size_t)m * QKV_LD + n] = (u16)f2bf(acc[im][in][r] + bv);
            }
        }
}

// ------- V transpose: Vt[h][t][k] <- qkv[k][h*192+128+t] ------------------
__global__ __launch_bounds__(256) void transpose_v(const u16* __restrict__ qkvb,
                                                   u16* __restrict__ Vt)
{
    __shared__ u16 tile[64][72];
    const int h = blockIdx.y, k0 = blockIdx.x << 6;
    const int t = threadIdx.x;
    {
        int r = t >> 2, cg = (t & 3) << 4;
        const u16* src = qkvb + (size_t)(k0 + r) * QKV_LD + h * 192 + 128 + cg;
        *(uint4*)&tile[r][cg]     = *(const uint4*)src;
        *(uint4*)&tile[r][cg + 8] = *(const uint4*)(src + 8);
    }
    __syncthreads();
    {
        int c = t >> 2, kg = (t & 3) << 4;
        u16 tmp[16];
#pragma unroll
        for (int j = 0; j < 16; ++j) tmp[j] = tile[kg + j][c];
        u16* dst = Vt + ((size_t)h * 64 + c) * NT + k0 + kg;
        *(uint4*)dst       = *(uint4*)&tmp[0];
        *(uint4*)(dst + 8) = *(uint4*)&tmp[8];
    }
}

// ------- scores + exp-rowsum: s = QK/8 (bf16, LDS-coalesced store) ----------
__global__ __launch_bounds__(256) void scores_mfma(const u16* __restrict__ qkvb,
                                                   u16* __restrict__ s,
                                                   float* __restrict__ zbuf)
{
    __shared__ u16 tile[128][144];   // stride 144 u16 = 288B: 16B-aligned rows
    const int h = blockIdx.z;
    const int kb = blockIdx.x << 7;
    const int qb = blockIdx.y << 7;
    const int w = threadIdx.x >> 6;
    const int q0 = qb + (w << 5);
    const int lane = threadIdx.x & 63;
    const int fr = lane & 15;
    const int kd = (lane >> 4) << 3;

    const u16* qbase = qkvb + (size_t)(q0 + fr) * QKV_LD + h * 192 + kd;
    const u16* kbase = qkvb + (size_t)(kb + fr) * QKV_LD + h * 192 + 64 + kd;

    short8 aq[2][2];
    aq[0][0] = *(const short8*)(qbase);
    aq[0][1] = *(const short8*)(qbase + 32);
    aq[1][0] = *(const short8*)(qbase + (size_t)16 * QKV_LD);
    aq[1][1] = *(const short8*)(qbase + (size_t)16 * QKV_LD + 32);

    v4f acc[2][8] = {};
#pragma unroll
    for (int nt = 0; nt < 8; ++nt) {
        short8 b0 = *(const short8*)(kbase + (size_t)nt * 16 * QKV_LD);
        short8 b1 = *(const short8*)(kbase + (size_t)nt * 16 * QKV_LD + 32);
        acc[0][nt] = __builtin_amdgcn_mfma_f32_16x16x32_bf16(aq[0][0], b0, acc[0][nt], 0, 0, 0);
        acc[0][nt] = __builtin_amdgcn_mfma_f32_16x16x32_bf16(aq[0][1], b1, acc[0][nt], 0, 0, 0);
        acc[1][nt] = __builtin_amdgcn_mfma_f32_16x16x32_bf16(aq[1][0], b0, acc[1][nt], 0, 0, 0);
        acc[1][nt] = __builtin_amdgcn_mfma_f32_16x16x32_bf16(aq[1][1], b1, acc[1][nt], 0, 0, 0);
    }
    const int qr = (lane >> 4) << 2;
    // scatter bf16 into LDS tile (local q row, local k col)
#pragma unroll
    for (int i = 0; i < 2; ++i)
#pragma unroll
        for (int nt = 0; nt < 8; ++nt)
#pragma unroll
            for (int r = 0; r < 4; ++r)
                tile[(w << 5) + (i << 4) + qr + r][(nt << 4) + fr] =
                    (u16)f2bf(acc[i][nt][r] * 0.125f);
    // per-row sum of exp (no max subtraction: |s| small, f32-safe)
    float es[2][4];
#pragma unroll
    for (int i = 0; i < 2; ++i)
#pragma unroll
        for (int r = 0; r < 4; ++r) {
            float sum = 0.f;
#pragma unroll
            for (int nt = 0; nt < 8; ++nt)
                sum += __expf(acc[i][nt][r] * 0.125f);
            es[i][r] = sum;
        }
#pragma unroll
    for (int off = 1; off < 16; off <<= 1)
#pragma unroll
        for (int i = 0; i < 2; ++i)
#pragma unroll
            for (int r = 0; r < 4; ++r)
                es[i][r] += __shfl_xor(es[i][r], off);
    if (fr == 0) {
#pragma unroll
        for (int i = 0; i < 2; ++i)
#pragma unroll
            for (int r = 0; r < 4; ++r)
                atomicAdd(zbuf + h * NT + q0 + (i << 4) + qr + r, es[i][r]);
    }
    __syncthreads();
    // coalesced global store: 16 threads x uint4 = 256B per row
    const int row0 = threadIdx.x >> 4;
    const int col = (threadIdx.x & 15) << 3;
#pragma unroll
    for (int l = 0; l < 8; ++l) {
        int row = row0 + (l << 4);
        *(uint4*)(s + ((size_t)h * NT + qb + row) * NT + kb + col) =
            *(uint4*)&tile[row][col];
    }
}

// ---- attn = softmax(s)+bias: triangle tiles, MFMA head-projection ----------
// Angle/phase/sincos numerics FROZEN (R3 path). Conflict-free LDS:
// biasl [h][qq][kk] strides 1057/33 (all phases <=2-way); ang stride 33.
__global__ __launch_bounds__(256) void bias_kernel(u16* __restrict__ s,
    const float* __restrict__ vec, const float* __restrict__ Wb,
    const float* __restrict__ bb, const float* __restrict__ zbuf)
{
    __shared__ float flds[32];
    __shared__ float vql[96], vkl[96];
    __shared__ float bbl[8];
    __shared__ float ang_lds[1057];          // [qq*33 + kk]
    __shared__ float biasl[8 * 1057];        // [h*1057 + qq*33 + kk]

    const int t = threadIdx.x;
    int b = blockIdx.x, tq = 0, rem = 64;
    while (b >= rem) { b -= rem; ++tq; --rem; }
    const int tk = tq + b;
    const int q0 = tq << 5, k0 = tk << 5;

    if (t < 32) flds[t] = __fdiv_rn(__fdiv_rn((float)t, 31.0f), 0.1f);
    else if (t < 128) vql[t - 32] = vec[q0 * 3 + (t - 32)];
    else if (t < 224) vkl[t - 128] = vec[k0 * 3 + (t - 128)];
    else if (t < 232) bbl[t - 224] = bb[t - 224];
    __syncthreads();

    // phase 1a: angles for all 1024 pairs (frozen numerics)
    {
        const int qq = t & 31, kb = (t >> 5) << 2;
        const float a0 = vql[qq * 3], a1 = vql[qq * 3 + 1], a2 = vql[qq * 3 + 2];
#pragma unroll
        for (int j = 0; j < 4; ++j) {
            const int kk = kb + j;
            float c0 = vkl[kk * 3], c1 = vkl[kk * 3 + 1], c2 = vkl[kk * 3 + 2];
            float dot = __fadd_rn(__fadd_rn(__fmul_rn(a0, c0), __fmul_rn(a1, c1)),
                                  __fmul_rn(a2, c2));
            float dotc = fminf(fmaxf(dot, 0.0f), 1.0f);
            ang_lds[qq * 33 + kk] = __fdiv_rn(acosf(dotc), 0.001f);
        }
    }
    __syncthreads();

    // phase 1b: sincos features -> MFMA projection onto 8 heads
    {
        const int w = t >> 6, lane = t & 63;
        const int fr = lane & 15, kd = (lane >> 4) << 3, qr = (lane >> 4) << 2;
        short8 BS, BC;
#pragma unroll
        for (int j = 0; j < 8; ++j) {
            float ws = (fr < 8) ? Wb[(kd + j) * 8 + fr] : 0.0f;
            float wc = (fr < 8) ? Wb[(32 + kd + j) * 8 + fr] : 0.0f;
            BS[j] = (short)f2bf(ws);
            BC[j] = (short)f2bf(wc);
        }
        for (int tt = w; tt < 64; tt += 4) {
            int p = (tt << 4) + fr;
            float ang = ang_lds[(p >> 5) * 33 + (p & 31)];
            short8 AS, AC;
#pragma unroll
            for (int j = 0; j < 8; ++j) {
                float ph = __fmul_rn(flds[kd + j], ang);
                float rv = ph * 0.15915494309189535f;
                float rf = rv - floorf(rv);
                AS[j] = (short)f2bf(__builtin_amdgcn_sinf(rf));
                AC[j] = (short)f2bf(__builtin_amdgcn_cosf(rf));
            }
            v4f c = {};
            c = __builtin_amdgcn_mfma_f32_16x16x32_bf16(AS, BS, c, 0, 0, 0);
            c = __builtin_amdgcn_mfma_f32_16x16x32_bf16(AC, BC, c, 0, 0, 0);
            if (fr < 8) {
#pragma unroll
                for (int r = 0; r < 4; ++r) {
                    int pp = (tt << 4) + qr + r;
                    biasl[fr * 1057 + (pp >> 5) * 33 + (pp & 31)] = c[r];
                }
            }
        }
    }
    __syncthreads();

    // phase 2: apply softmax + bias, coalesced RMW, both orientations
    const int r = t >> 3;
    const int cg = (t & 7) << 2;
    {
        const int q = q0 + r;
#pragma unroll
        for (int h = 0; h < 8; ++h) {
            const float iz = 1.0f / zbuf[h * NT + q];
            const float bv = bbl[h];
            const size_t base = ((size_t)h * NT + q) * NT + k0 + cg;
            uint2 raw = *(const uint2*)(s + base);
            float v[4]; unpack4(raw, v);
            unsigned int o[4];
#pragma unroll
            for (int j = 0; j < 4; ++j) {
                float bias = biasl[h * 1057 + r * 33 + cg + j];
                o[j] = f2bf(__expf(v[j]) * iz + bias + bv);
            }
            uint2 wv; wv.x = o[0] | (o[1] << 16); wv.y = o[2] | (o[3] << 16);
            *(uint2*)(s + base) = wv;
        }
    }
    if (tk != tq) {
        const int q = k0 + r;
#pragma unroll
        for (int h = 0; h < 8; ++h) {
            const float iz = 1.0f / zbuf[h * NT + q];
            const float bv = bbl[h];
            const size_t base = ((size_t)h * NT + q) * NT + q0 + cg;
            uint2 raw = *(const uint2*)(s + base);
            float v[4]; unpack4(raw, v);
            unsigned int o[4];
#pragma unroll
            for (int j = 0; j < 4; ++j) {
                float bias = biasl[h * 1057 + (cg + j) * 33 + r];
                o[j] = f2bf(__expf(v[j]) * iz + bias + bv);
            }
            uint2 wv; wv.x = o[0] | (o[1] << 16); wv.y = o[2] | (o[3] << 16);
            *(uint2*)(s + base) = wv;
        }
    }
}

// ------- y_part = attn @ V via bf16 MFMA (split-K=4), frags from global ----
__global__ __launch_bounds__(256) void attnv_mfma(const u16* __restrict__ attn,
    const u16* __restrict__ Vt, float* __restrict__ ypart)
{
    const int h = blockIdx.y, z = blockIdx.z;
    const int q0 = (blockIdx.x << 6) + ((threadIdx.x >> 6) << 4);
    const int lane = threadIdx.x & 63;
    const int fr = lane & 15;
    const int kd = (lane >> 4) << 3;
    const int kbase = z << 9;

    const u16* arow  = attn + (size_t)(h * NT + q0 + fr) * NT + kbase + kd;
    const u16* vbase = Vt + ((size_t)h * 64 + fr) * NT + kbase + kd;

    v4f c[4] = {};
    for (int ks = 0; ks < 512; ks += 32) {
        short8 a = *(const short8*)(arow + ks);
#pragma unroll
        for (int nt = 0; nt < 4; ++nt) {
            short8 bv = *(const short8*)(vbase + (size_t)nt * 16 * NT + ks);
            c[nt] = __builtin_amdgcn_mfma_f32_16x16x32_bf16(a, bv, c[nt], 0, 0, 0);
        }
    }
    float* yp = ypart + (size_t)z * NT * EMBD;
    const int qr = (lane >> 4) << 2;
#pragma unroll
    for (int nt = 0; nt < 4; ++nt)
#pragma unroll
        for (int r = 0; r < 4; ++r)
            yp[(size_t)(q0 + qr + r) * EMBD + (h << 6) + (nt << 4) + fr] = c[nt][r];
}

// ------- reduce 4 y-partials -> bf16 hi/lo ----------------------------------
__global__ __launch_bounds__(256) void reduce_y(const float* __restrict__ parts,
    u16* __restrict__ yh, u16* __restrict__ yl)
{
    const int MN = NT * EMBD;
    int i = (blockIdx.x * 256 + threadIdx.x) << 2;
    float4 acc = *(const float4*)(parts + i);
#pragma unroll
    for (int sp = 1; sp < 4; ++sp) {
        float4 p = *(const float4*)(parts + (size_t)sp * MN + i);
        acc.x += p.x; acc.y += p.y; acc.z += p.z; acc.w += p.w;
    }
    float f[4] = {acc.x, acc.y, acc.z, acc.w};
    unsigned int hi[4], lo[4];
#pragma unroll
    for (int j = 0; j < 4; ++j) {
        hi[j] = f2bf(f[j]);
        lo[j] = f2bf(f[j] - bf2f(hi[j]));
    }
    uint2 wh; wh.x = hi[0] | (hi[1] << 16); wh.y = hi[2] | (hi[3] << 16);
    uint2 wl; wl.x = lo[0] | (lo[1] << 16); wl.y = lo[2] | (lo[3] << 16);
    *(uint2*)(yh + i) = wh;
    *(uint2*)(yl + i) = wl;
}

// ------- out = y @ Wout + bout via split-precision bf16 MFMA ----------------
__global__ __launch_bounds__(256) void gemm_out_mfma(const u16* __restrict__ yh,
    const u16* __restrict__ yl, const u16* __restrict__ wh,
    const u16* __restrict__ wl, const float* __restrict__ bias,
    float* __restrict__ out)
{
    const int n0 = blockIdx.x << 6, m0 = blockIdx.y << 6;
    const int w = threadIdx.x >> 6, lane = threadIdx.x & 63;
    const int wm = w >> 1, wn = w & 1;
    const int fr = lane & 15, kd = (lane >> 4) << 3;

    const u16* ah0 = yh + (size_t)(m0 + wm * 32 + fr) * EMBD + kd;
    const u16* al0 = yl + (size_t)(m0 + wm * 32 + fr) * EMBD + kd;
    const u16* bh0 = wh + (size_t)(n0 + wn * 32 + fr) * EMBD + kd;
    const u16* bl0 = wl + (size_t)(n0 + wn * 32 + fr) * EMBD + kd;

    v4f acc[2][2] = {};
    for (int kc = 0; kc < EMBD; kc += 32) {
        short8 a_h[2], a_l[2], b_h[2], b_l[2];
#pragma unroll
        for (int im = 0; im < 2; ++im) {
            a_h[im] = *(const short8*)(ah0 + (size_t)im * 16 * EMBD + kc);
            a_l[im] = *(const short8*)(al0 + (size_t)im * 16 * EMBD + kc);
        }
#pragma unroll
        for (int in = 0; in < 2; ++in) {
            b_h[in] = *(const short8*)(bh0 + (size_t)in * 16 * EMBD + kc);
            b_l[in] = *(const short8*)(bl0 + (size_t)in * 16 * EMBD + kc);
        }
#pragma unroll
        for (int im = 0; im < 2; ++im)
#pragma unroll
            for (int in = 0; in < 2; ++in) {
                acc[im][in] = __builtin_amdgcn_mfma_f32_16x16x32_bf16(a_h[im], b_h[in], acc[im][in], 0, 0, 0);
                acc[im][in] = __builtin_amdgcn_mfma_f32_16x16x32_bf16(a_h[im], b_l[in], acc[im][in], 0, 0, 0);
                acc[im][in] = __builtin_amdgcn_mfma_f32_16x16x32_bf16(a_l[im], b_h[in], acc[im][in], 0, 0, 0);
            }
    }
    const int qr = (lane >> 4) << 2;
#pragma unroll
    for (int im = 0; im < 2; ++im)
#pragma unroll
        for (int in = 0; in < 2; ++in) {
            int n = n0 + wn * 32 + in * 16 + fr;
            float bv = bias[n];
#pragma unroll
            for (int r = 0; r < 4; ++r) {
                int m = m0 + wm * 32 + im * 16 + qr + r;
                out[(size_t)m * EMBD + n] = acc[im][in][r] + bv;
            }
        }
}

extern "C" void kernel_launch(void* const* d_in, const int* in_sizes, int n_in,
                              void* d_out, int out_size, void* d_ws, size_t ws_size,
                              hipStream_t stream)
{
    const float* x    = (const float*)d_in[0];
    const float* vec  = (const float*)d_in[1];
    const float* Wqkv = (const float*)d_in[2];
    const float* bqkv = (const float*)d_in[3];
    const float* Wb   = (const float*)d_in[4];
    const float* bb   = (const float*)d_in[5];
    const float* Wout = (const float*)d_in[6];
    const float* bout = (const float*)d_in[7];
    float* out = (float*)d_out;

    char* ws = (char*)d_ws;
    u16*   qkvb  = (u16*)(ws);                      //  6,291,456
    u16*   sbuf  = (u16*)(ws + 6291456);            // 67,108,864
    u16*   Vt    = (u16*)(ws + 73400320);           //  2,097,152
    float* zbuf  = (float*)(ws + 75497472);         //     65,536
    u16*   yh    = (u16*)(ws + 75628544);           //  2,097,152
    u16*   yl    = (u16*)(ws + 77725696);           //  2,097,152
    float* parts = (float*)(ws + 79822848);         // 16,777,216
    // transient aliases into the parts region (sequenced by launch order):
    u16*   xh    = (u16*)(ws + 79822848);           // consumed by gemm_qkv
    u16*   xl    = (u16*)(ws + 81920000);
    u16*   wth   = (u16*)(ws + 84017152);
    u16*   wtl   = (u16*)(ws + 85590016);
    u16*   woth  = (u16*)(ws + 79822848);           // written after reduce_y
    u16*   wotl  = (u16*)(ws + 80347136);
    // total: 96,600,064 B

    hipMemsetAsync(zbuf, 0, NH * NT * sizeof(float), stream);
    split_x<<<1024, 256, 0, stream>>>(x, xh, xl);
    split_wt<<<dim3(24, 8), 256, 0, stream>>>(Wqkv, wth, wtl, QKV_LD);
    gemm_qkv_mfma<<<dim3(24, 32), 256, 0, stream>>>(xh, xl, wth, wtl, bqkv, qkvb);
    transpose_v<<<dim3(32, 8), 256, 0, stream>>>(qkvb, Vt);
    scores_mfma<<<dim3(16, 16, 8), 256, 0, stream>>>(qkvb, sbuf, zbuf);
    bias_kernel<<<2080, 256, 0, stream>>>(sbuf, vec, Wb, bb, zbuf);
    attnv_mfma<<<dim3(32, 8, 4), 256, 0, stream>>>(sbuf, Vt, parts);
    reduce_y<<<1024, 256, 0, stream>>>(parts, yh, yl);
    split_wt<<<dim3(8, 8), 256, 0, stream>>>(Wout, woth, wotl, EMBD);
    gemm_out_mfma<<<dim3(8, 32), 256, 0, stream>>>(yh, yl, woth, wotl, bout, out);
}